// Round 4
// baseline (21994.398 us; speedup 1.0000x reference)
//
#include <hip/hip_runtime.h>
#include <hip/hip_bf16.h>
#include <cstdint>

typedef _Float16 h2 __attribute__((ext_vector_type(2)));
typedef _Float16 h4 __attribute__((ext_vector_type(4)));
typedef _Float16 h8 __attribute__((ext_vector_type(8)));
typedef float f4 __attribute__((ext_vector_type(4)));

#define S_LEN 512
#define BATCH 64
#define DM    512
#define HID   768

static __device__ __forceinline__ h2 mk2f(float a, float b) {
  h2 t; t.x = (_Float16)a; t.y = (_Float16)b; return t;
}

// ---------------------------------------------------------------------------
// Kernel A: xg[dir] = gather(emb, ids) @ Wi^T + bi   (fp32 in, fp16 out)
// Chunked: covers CH sequence steps per direction, starting at s0_f / s0_b.
// Output layout (chunk-local sl): xg[((sl*3 + gate)*64 + b)*768 + j]
//   -> scan lane reads 4 contiguous j as one 8B load per gate.
// ---------------------------------------------------------------------------
__global__ __launch_bounds__(256) void gemm1_kernel(
    const int* __restrict__ ids, const float* __restrict__ emb,
    const float* __restrict__ Wi_f, const float* __restrict__ bi_f,
    const float* __restrict__ Wi_b, const float* __restrict__ bi_b,
    int s0_f, int s0_b,
    _Float16* __restrict__ xg_f, _Float16* __restrict__ xg_b)
{
  const int mt  = blockIdx.x;      // 0..CH/2-1  (local M tiles of 128)
  const int nty = blockIdx.y;      // 0..35
  const int dir = nty / 18;
  const int nt  = nty - dir * 18;  // 0..17   (N = 2304 / 128)
  const float* __restrict__ Wi = dir ? Wi_b : Wi_f;
  const float* __restrict__ bi = dir ? bi_b : bi_f;
  _Float16*   __restrict__ xg  = dir ? xg_b : xg_f;
  const int s0 = dir ? s0_b : s0_f;

  __shared__ int ids_s[128];
  __shared__ _Float16 As[128][38];   // row stride 38 halves -> conflict-light
  __shared__ _Float16 Bs[128][38];

  const int tid = threadIdx.x;
  if (tid < 128) {
    int m = mt * 128 + tid;          // local m = sl*64 + b
    ids_s[tid] = ids[(m & 63) * S_LEN + s0 + (m >> 6)];   // ids[b][s0+sl]
  }

  float acc[8][8];
#pragma unroll
  for (int i = 0; i < 8; ++i)
#pragma unroll
    for (int j = 0; j < 8; ++j) acc[i][j] = 0.f;

  const int tr = tid >> 4, tc = tid & 15;
  const int r0 = tr * 8, c0 = tc * 8;
  const int lr = tid >> 1, lh = tid & 1;

  __syncthreads();

  for (int kt = 0; kt < DM; kt += 32) {
    {
      const float* srcA = emb + (size_t)ids_s[lr] * DM + kt + lh * 16;
      const float* srcB = Wi + (size_t)(nt * 128 + lr) * DM + kt + lh * 16;
      float4 a0 = ((const float4*)srcA)[0], a1 = ((const float4*)srcA)[1];
      float4 a2 = ((const float4*)srcA)[2], a3 = ((const float4*)srcA)[3];
      float4 b0 = ((const float4*)srcB)[0], b1v = ((const float4*)srcB)[1];
      float4 b2v = ((const float4*)srcB)[2], b3 = ((const float4*)srcB)[3];
      h2* da = (h2*)&As[lr][lh * 16];
      h2* db = (h2*)&Bs[lr][lh * 16];
      da[0] = mk2f(a0.x, a0.y);  da[1] = mk2f(a0.z, a0.w);
      da[2] = mk2f(a1.x, a1.y);  da[3] = mk2f(a1.z, a1.w);
      da[4] = mk2f(a2.x, a2.y);  da[5] = mk2f(a2.z, a2.w);
      da[6] = mk2f(a3.x, a3.y);  da[7] = mk2f(a3.z, a3.w);
      db[0] = mk2f(b0.x, b0.y);  db[1] = mk2f(b0.z, b0.w);
      db[2] = mk2f(b1v.x, b1v.y); db[3] = mk2f(b1v.z, b1v.w);
      db[4] = mk2f(b2v.x, b2v.y); db[5] = mk2f(b2v.z, b2v.w);
      db[6] = mk2f(b3.x, b3.y);  db[7] = mk2f(b3.z, b3.w);
    }
    __syncthreads();
#pragma unroll
    for (int kp = 0; kp < 16; ++kp) {
      h2 av[8], bv[8];
#pragma unroll
      for (int i = 0; i < 8; ++i) av[i] = *(const h2*)&As[r0 + i][kp * 2];
#pragma unroll
      for (int j = 0; j < 8; ++j) bv[j] = *(const h2*)&Bs[c0 + j][kp * 2];
#pragma unroll
      for (int i = 0; i < 8; ++i)
#pragma unroll
        for (int j = 0; j < 8; ++j)
          acc[i][j] = __builtin_amdgcn_fdot2(av[i], bv[j], acc[i][j], false);
    }
    __syncthreads();
  }

  float biv[8];
#pragma unroll
  for (int j = 0; j < 8; ++j) biv[j] = bi[nt * 128 + c0 + j];
  const int n0 = nt * 128 + c0;          // 8 consecutive n, same gate (768%8==0)
  const int gate = n0 / 768;
  const int jj = n0 - gate * 768;
#pragma unroll
  for (int i = 0; i < 8; ++i) {
    int m = mt * 128 + r0 + i;
    int sl = m >> 6, b = m & 63;         // chunk-local step, batch
    h8 v;
#pragma unroll
    for (int j = 0; j < 8; ++j) v[j] = (_Float16)(acc[i][j] + biv[j]);
    *(h8*)&xg[(((size_t)sl * 3 + gate) * 64 + b) * 768 + jj] = v;
  }
}

// ---------------------------------------------------------------------------
// Kernel B: MFMA GRU scan, weights register-resident.
// 24 blocks x 1024 threads. Block = (dir, bgroup of 16, jb third of units).
// Wave w owns 16 output units (jt = jb*16+w), all K=768, 3 gates as MFMA
// A-fragments (288 VGPRs). h: fp32 master in regs (lane owns 4 (j,b) pairs),
// fp16 [b][k] exchange buffer double-buffered by step parity.
// Sync domain per step: 3 blocks (atomic counter per (dir,bgroup) per step).
// ---------------------------------------------------------------------------
__global__ __launch_bounds__(1024, 4) void scan_mfma_kernel(
    const float* __restrict__ Wh_f, const float* __restrict__ bh_f,
    const float* __restrict__ Wh_b, const float* __restrict__ bh_b,
    const _Float16* __restrict__ xg_f, const _Float16* __restrict__ xg_b,
    _Float16* __restrict__ hx,      // [dir][parity][64][768] fp16
    float* __restrict__ hfin,       // [dir][64][768] fp32 chunk-save / final
    unsigned* __restrict__ bars,    // [2*4][512]
    int step0, int nsteps)
{
  const int blk = blockIdx.x;       // 0..23
  const int dir = blk / 12;
  const int l   = blk - dir * 12;   // 0..11
  const int bg  = l / 3;            // batch group 0..3
  const int jb  = l - bg * 3;       // unit third 0..2

  const float* __restrict__ Wh = dir ? Wh_b : Wh_f;
  const float* __restrict__ bh = dir ? bh_b : bh_f;
  const _Float16* __restrict__ xg = dir ? xg_b : xg_f;
  _Float16* __restrict__ hxd = hx + (size_t)dir * 2 * 64 * 768;
  float*    __restrict__ hfd = hfin + (size_t)dir * 64 * 768;
  unsigned* __restrict__ bar = bars + (dir * 4 + bg) * 512;

  const int tid = threadIdx.x;
  const int w   = tid >> 6;         // wave 0..15
  const int L   = tid & 63;
  const int lh  = L >> 4;           // 0..3
  const int ln  = L & 15;           // 0..15
  const int jt  = jb * 16 + w;      // unit tile 0..47
  const int jrow = jt * 16 + ln;    // A-fragment row (j)
  const int j0l  = jt * 16 + lh * 4;  // 4 owned units j0l..j0l+3
  const int bglob = bg * 16 + ln;   // owned batch column

  // ---- load Wh as A-fragments: A[gate][ks], element e -> Wh[j=jrow][ks*32+lh*8+e]
  h8 A[3][24];
#pragma unroll
  for (int g = 0; g < 3; ++g)
#pragma unroll
    for (int ks = 0; ks < 24; ++ks) {
      const float* src = Wh + (size_t)(g * 768 + jrow) * 768 + ks * 32 + lh * 8;
      float4 w0 = ((const float4*)src)[0];
      float4 w1 = ((const float4*)src)[1];
      h8 a;
      a[0] = (_Float16)w0.x; a[1] = (_Float16)w0.y;
      a[2] = (_Float16)w0.z; a[3] = (_Float16)w0.w;
      a[4] = (_Float16)w1.x; a[5] = (_Float16)w1.y;
      a[6] = (_Float16)w1.z; a[7] = (_Float16)w1.w;
      A[g][ks] = a;
    }

  // ---- per-lane hidden biases for owned units
  f4 bhv[3];
#pragma unroll
  for (int g = 0; g < 3; ++g) bhv[g] = *(const f4*)&bh[g * 768 + j0l];

  // ---- fp32 h master (4 owned (j,b) values)
  f4 hm;
  if (step0 == 0) { hm[0] = 0.f; hm[1] = 0.f; hm[2] = 0.f; hm[3] = 0.f; }
  else hm = *(const f4*)&hfd[(size_t)bglob * 768 + j0l];

  for (int t = 0; t < nsteps; ++t) {
    const int sg = step0 + t;
    const int pin = sg & 1, pout = pin ^ 1;
    const _Float16* __restrict__ hin = hxd + (size_t)pin * 64 * 768;

    // B-fragments: element e -> h[k=ks*32+lh*8+e][b=bglob]  (hx stored [b][k])
    h8 Bf[24];
#pragma unroll
    for (int ks = 0; ks < 24; ++ks)
      Bf[ks] = *(const h8*)&hin[(size_t)bglob * 768 + ks * 32 + lh * 8];

    f4 Cr, Cz, Cn;
    Cr[0]=0.f;Cr[1]=0.f;Cr[2]=0.f;Cr[3]=0.f;
    Cz = Cr; Cn = Cr;
#pragma unroll
    for (int ks = 0; ks < 24; ++ks) {
      Cr = __builtin_amdgcn_mfma_f32_16x16x32_f16(A[0][ks], Bf[ks], Cr, 0, 0, 0);
      Cz = __builtin_amdgcn_mfma_f32_16x16x32_f16(A[1][ks], Bf[ks], Cz, 0, 0, 0);
      Cn = __builtin_amdgcn_mfma_f32_16x16x32_f16(A[2][ks], Bf[ks], Cn, 0, 0, 0);
    }

    // xg: [((lsl*3+gate)*64 + b)*768 + j]
    const int lsl = dir ? (nsteps - 1 - t) : t;
    const _Float16* xrow = xg + (((size_t)lsl * 3) * 64 + bglob) * 768 + j0l;
    h4 xr4 = *(const h4*)xrow;
    h4 xz4 = *(const h4*)(xrow + (size_t)64 * 768);
    h4 xn4 = *(const h4*)(xrow + (size_t)2 * 64 * 768);

    f4 hnew;
    h4 st;
#pragma unroll
    for (int r = 0; r < 4; ++r) {
      float rr = 1.f / (1.f + __expf(-((float)xr4[r] + Cr[r] + bhv[0][r])));
      float zz = 1.f / (1.f + __expf(-((float)xz4[r] + Cz[r] + bhv[1][r])));
      float nn = tanhf((float)xn4[r] + rr * (Cn[r] + bhv[2][r]));
      hnew[r] = (1.f - zz) * nn + zz * hm[r];
      st[r] = (_Float16)hnew[r];
    }
    hm = hnew;
    *(h4*)&hxd[((size_t)pout * 64 + bglob) * 768 + j0l] = st;

    __syncthreads();                       // drains vmcnt before barrier
    if (tid == 0) {
      __threadfence();                     // release h writes (agent scope)
      atomicAdd(&bar[sg], 1u);
      while (__hip_atomic_load(&bar[sg], __ATOMIC_RELAXED, __HIP_MEMORY_SCOPE_AGENT) < 3u) { }
      __threadfence();                     // acquire side
    }
    __syncthreads();
  }

  // save h (chunk boundary or final) - same lane owns same (j,b) next launch
  *(f4*)&hfd[(size_t)bglob * 768 + j0l] = hm;
}

// ---------------------------------------------------------------------------
// MLP head.  hfin layout: [dir][b][j] fp32.
// ---------------------------------------------------------------------------
__global__ __launch_bounds__(256) void mlp1_kernel(
    const float* __restrict__ hfin, const float* __restrict__ W1,
    const float* __restrict__ b1, float* __restrict__ hid)
{
  const int c = blockIdx.x * 4 + (threadIdx.x >> 6);
  const int b = threadIdx.x & 63;
  const float* __restrict__ hf = hfin + (size_t)b * 768;
  const float* __restrict__ hb = hfin + (size_t)(64 + b) * 768;
  const float* __restrict__ w = W1 + (size_t)c * 1536;
  float acc = b1[c];
  for (int k = 0; k < 768; k += 4) {
    float4 hv = *(const float4*)&hf[k];
    float4 wv = *(const float4*)&w[k];
    acc += hv.x * wv.x + hv.y * wv.y + hv.z * wv.z + hv.w * wv.w;
  }
  for (int k = 0; k < 768; k += 4) {
    float4 hv = *(const float4*)&hb[k];
    float4 wv = *(const float4*)&w[768 + k];
    acc += hv.x * wv.x + hv.y * wv.y + hv.z * wv.z + hv.w * wv.w;
  }
  hid[(size_t)c * 64 + b] = fmaxf(acc, 0.f);
}

__global__ void mlp2_kernel(const float* __restrict__ hid,
                            const float* __restrict__ W2,
                            const float* __restrict__ b2,
                            float* __restrict__ out)
{
  const int tid = threadIdx.x;      // 128 threads
  const int b = tid & 63, cls = tid >> 6;
  const float* __restrict__ w = W2 + cls * 768;
  float acc = b2[cls];
  for (int k = 0; k < 768; ++k) acc += hid[(size_t)k * 64 + b] * w[k];
  out[b * 2 + cls] = acc;
}

// ---------------------------------------------------------------------------
extern "C" void kernel_launch(void* const* d_in, const int* in_sizes, int n_in,
                              void* d_out, int out_size, void* d_ws, size_t ws_size,
                              hipStream_t stream)
{
  const int*   ids  = (const int*)d_in[0];
  const float* emb  = (const float*)d_in[1];
  const float* Wi_f = (const float*)d_in[2];
  const float* Wh_f = (const float*)d_in[3];
  const float* bi_f = (const float*)d_in[4];
  const float* bh_f = (const float*)d_in[5];
  const float* Wi_b = (const float*)d_in[6];
  const float* Wh_b = (const float*)d_in[7];
  const float* bi_b = (const float*)d_in[8];
  const float* bh_b = (const float*)d_in[9];
  const float* W1   = (const float*)d_in[10];
  const float* b1   = (const float*)d_in[11];
  const float* W2   = (const float*)d_in[12];
  const float* b2   = (const float*)d_in[13];
  float* out = (float*)d_out;

  // state sizes (elements)
  const size_t N_HX   = (size_t)2 * 2 * 64 * 768;   // halves
  const size_t N_HFIN = (size_t)2 * 64 * 768;       // floats
  const size_t N_HID  = (size_t)HID * BATCH;        // floats
  const size_t N_BAR  = 8 * 512;                    // uints
  const size_t state_bytes = N_HX * 2 + N_HFIN * 4 + N_HID * 4 + N_BAR * 4;

  // choose chunk size: largest CH with 2*CH*64*2304 fp16 xg + state <= ws
  int CH = 512;
  while (CH > 8) {
    size_t need = (size_t)4 * CH * 64 * 2304 + state_bytes;
    if (need <= ws_size) break;
    CH >>= 1;
  }
  const size_t SZ_XG = (size_t)CH * 64 * 2304;      // halves per direction

  char* ws = (char*)d_ws;
  _Float16* xg_f = (_Float16*)ws;
  _Float16* xg_b = xg_f + SZ_XG;
  _Float16* hx   = xg_b + SZ_XG;
  float*    hfin = (float*)(hx + N_HX);
  float*    hid  = hfin + N_HFIN;
  unsigned* bars = (unsigned*)(hid + N_HID);

  // zero hx + hfin + hid + barriers (contiguous region) every launch
  size_t zbytes = N_HX * 2 + N_HFIN * 4 + N_HID * 4 + N_BAR * 4;
  (void)hipMemsetAsync(hx, 0, zbytes, stream);

  const int nch = 512 / CH;
  for (int c = 0; c < nch; ++c) {
    const int s0f = c * CH;                 // fwd window start
    const int s0b = 512 - (c + 1) * CH;     // bwd window start
    gemm1_kernel<<<dim3(CH / 2, 36), 256, 0, stream>>>(
        ids, emb, Wi_f, bi_f, Wi_b, bi_b, s0f, s0b, xg_f, xg_b);
    scan_mfma_kernel<<<24, 1024, 0, stream>>>(
        Wh_f, bh_f, Wh_b, bh_b, xg_f, xg_b, hx, hfin, bars, c * CH, CH);
  }
  mlp1_kernel<<<192, 256, 0, stream>>>(hfin, W1, b1, hid);
  mlp2_kernel<<<1, 128, 0, stream>>>(hid, W2, b2, out);
}

// Round 5
// 7147.353 us; speedup vs baseline: 3.0773x; 3.0773x over previous
//
#include <hip/hip_runtime.h>
#include <hip/hip_bf16.h>
#include <cstdint>

typedef _Float16 h2 __attribute__((ext_vector_type(2)));
typedef _Float16 h4 __attribute__((ext_vector_type(4)));
typedef _Float16 h8 __attribute__((ext_vector_type(8)));
typedef float f4 __attribute__((ext_vector_type(4)));

#define S_LEN 512
#define BATCH 64
#define DM    512
#define HID   768

static __device__ __forceinline__ h2 mk2f(float a, float b) {
  h2 t; t.x = (_Float16)a; t.y = (_Float16)b; return t;
}

// ---------------------------------------------------------------------------
// Kernel A: xg[dir] = gather(emb, ids) @ Wi^T + bi   (fp32 in, fp16 out)
// Chunked: covers CH sequence steps per direction, starting at s0_f / s0_b.
// Output layout (chunk-local sl): xg[((sl*3 + gate)*64 + b)*768 + j]
//   -> scan lane reads 4 contiguous j as one 8B load per gate.
// ---------------------------------------------------------------------------
__global__ __launch_bounds__(256) void gemm1_kernel(
    const int* __restrict__ ids, const float* __restrict__ emb,
    const float* __restrict__ Wi_f, const float* __restrict__ bi_f,
    const float* __restrict__ Wi_b, const float* __restrict__ bi_b,
    int s0_f, int s0_b,
    _Float16* __restrict__ xg_f, _Float16* __restrict__ xg_b)
{
  const int mt  = blockIdx.x;      // 0..CH/2-1  (local M tiles of 128)
  const int nty = blockIdx.y;      // 0..35
  const int dir = nty / 18;
  const int nt  = nty - dir * 18;  // 0..17   (N = 2304 / 128)
  const float* __restrict__ Wi = dir ? Wi_b : Wi_f;
  const float* __restrict__ bi = dir ? bi_b : bi_f;
  _Float16*   __restrict__ xg  = dir ? xg_b : xg_f;
  const int s0 = dir ? s0_b : s0_f;

  __shared__ int ids_s[128];
  __shared__ _Float16 As[128][38];   // row stride 38 halves -> conflict-light
  __shared__ _Float16 Bs[128][38];

  const int tid = threadIdx.x;
  if (tid < 128) {
    int m = mt * 128 + tid;          // local m = sl*64 + b
    ids_s[tid] = ids[(m & 63) * S_LEN + s0 + (m >> 6)];   // ids[b][s0+sl]
  }

  float acc[8][8];
#pragma unroll
  for (int i = 0; i < 8; ++i)
#pragma unroll
    for (int j = 0; j < 8; ++j) acc[i][j] = 0.f;

  const int tr = tid >> 4, tc = tid & 15;
  const int r0 = tr * 8, c0 = tc * 8;
  const int lr = tid >> 1, lh = tid & 1;

  __syncthreads();

  for (int kt = 0; kt < DM; kt += 32) {
    {
      const float* srcA = emb + (size_t)ids_s[lr] * DM + kt + lh * 16;
      const float* srcB = Wi + (size_t)(nt * 128 + lr) * DM + kt + lh * 16;
      float4 a0 = ((const float4*)srcA)[0], a1 = ((const float4*)srcA)[1];
      float4 a2 = ((const float4*)srcA)[2], a3 = ((const float4*)srcA)[3];
      float4 b0 = ((const float4*)srcB)[0], b1v = ((const float4*)srcB)[1];
      float4 b2v = ((const float4*)srcB)[2], b3 = ((const float4*)srcB)[3];
      h2* da = (h2*)&As[lr][lh * 16];
      h2* db = (h2*)&Bs[lr][lh * 16];
      da[0] = mk2f(a0.x, a0.y);  da[1] = mk2f(a0.z, a0.w);
      da[2] = mk2f(a1.x, a1.y);  da[3] = mk2f(a1.z, a1.w);
      da[4] = mk2f(a2.x, a2.y);  da[5] = mk2f(a2.z, a2.w);
      da[6] = mk2f(a3.x, a3.y);  da[7] = mk2f(a3.z, a3.w);
      db[0] = mk2f(b0.x, b0.y);  db[1] = mk2f(b0.z, b0.w);
      db[2] = mk2f(b1v.x, b1v.y); db[3] = mk2f(b1v.z, b1v.w);
      db[4] = mk2f(b2v.x, b2v.y); db[5] = mk2f(b2v.z, b2v.w);
      db[6] = mk2f(b3.x, b3.y);  db[7] = mk2f(b3.z, b3.w);
    }
    __syncthreads();
#pragma unroll
    for (int kp = 0; kp < 16; ++kp) {
      h2 av[8], bv[8];
#pragma unroll
      for (int i = 0; i < 8; ++i) av[i] = *(const h2*)&As[r0 + i][kp * 2];
#pragma unroll
      for (int j = 0; j < 8; ++j) bv[j] = *(const h2*)&Bs[c0 + j][kp * 2];
#pragma unroll
      for (int i = 0; i < 8; ++i)
#pragma unroll
        for (int j = 0; j < 8; ++j)
          acc[i][j] = __builtin_amdgcn_fdot2(av[i], bv[j], acc[i][j], false);
    }
    __syncthreads();
  }

  float biv[8];
#pragma unroll
  for (int j = 0; j < 8; ++j) biv[j] = bi[nt * 128 + c0 + j];
  const int n0 = nt * 128 + c0;          // 8 consecutive n, same gate (768%8==0)
  const int gate = n0 / 768;
  const int jj = n0 - gate * 768;
#pragma unroll
  for (int i = 0; i < 8; ++i) {
    int m = mt * 128 + r0 + i;
    int sl = m >> 6, b = m & 63;         // chunk-local step, batch
    h8 v;
#pragma unroll
    for (int j = 0; j < 8; ++j) v[j] = (_Float16)(acc[i][j] + biv[j]);
    *(h8*)&xg[(((size_t)sl * 3 + gate) * 64 + b) * 768 + jj] = v;
  }
}

// ---------------------------------------------------------------------------
// Kernel B: MFMA GRU scan, weights register-resident.
// 96 blocks x 256 threads, __launch_bounds__(256,1) -> up to 512 VGPR/lane,
// 1 wave/SIMD, 1 block/CU. Block = (dir, bgroup of 16, jb twelfth of units).
// Wave w owns 16 output units (jt = jb*4+w), all K=768, 3 gates as MFMA
// A-fragments (288 VGPRs, truly register-resident now). h: fp32 master in
// regs (lane owns 4 (j,b)), fp16 [b][k] exchange, double-buffered by parity.
// Sync domain per step: 12 blocks (atomic counter per (dir,bgroup), per step).
// ---------------------------------------------------------------------------
__global__ __launch_bounds__(256, 1) void scan_mfma_kernel(
    const float* __restrict__ Wh_f, const float* __restrict__ bh_f,
    const float* __restrict__ Wh_b, const float* __restrict__ bh_b,
    const _Float16* __restrict__ xg_f, const _Float16* __restrict__ xg_b,
    _Float16* __restrict__ hx,      // [dir][parity][64][768] fp16
    float* __restrict__ hfin,       // [dir][64][768] fp32 chunk-save / final
    unsigned* __restrict__ bars,    // [2*4][512]
    int step0, int nsteps)
{
  const int blk = blockIdx.x;       // 0..95
  const int dir = blk / 48;
  const int l   = blk - dir * 48;   // 0..47
  const int bg  = l / 12;           // batch group 0..3
  const int jb  = l - bg * 12;      // unit twelfth 0..11

  const float* __restrict__ Wh = dir ? Wh_b : Wh_f;
  const float* __restrict__ bh = dir ? bh_b : bh_f;
  const _Float16* __restrict__ xg = dir ? xg_b : xg_f;
  _Float16* __restrict__ hxd = hx + (size_t)dir * 2 * 64 * 768;
  float*    __restrict__ hfd = hfin + (size_t)dir * 64 * 768;
  unsigned* __restrict__ bar = bars + (dir * 4 + bg) * 512;

  const int tid = threadIdx.x;
  const int w   = tid >> 6;         // wave 0..3
  const int L   = tid & 63;
  const int lh  = L >> 4;           // 0..3
  const int ln  = L & 15;           // 0..15
  const int jt  = jb * 4 + w;       // unit tile 0..47
  const int jrow = jt * 16 + ln;    // A-fragment row (j)
  const int j0l  = jt * 16 + lh * 4;  // 4 owned units j0l..j0l+3
  const int bglob = bg * 16 + ln;   // owned batch column

  // ---- load Wh as A-fragments: A[gate][ks], element e -> Wh[j=jrow][ks*32+lh*8+e]
  h8 A[3][24];
#pragma unroll
  for (int g = 0; g < 3; ++g)
#pragma unroll
    for (int ks = 0; ks < 24; ++ks) {
      const float* src = Wh + (size_t)(g * 768 + jrow) * 768 + ks * 32 + lh * 8;
      float4 w0 = ((const float4*)src)[0];
      float4 w1 = ((const float4*)src)[1];
      h8 a;
      a[0] = (_Float16)w0.x; a[1] = (_Float16)w0.y;
      a[2] = (_Float16)w0.z; a[3] = (_Float16)w0.w;
      a[4] = (_Float16)w1.x; a[5] = (_Float16)w1.y;
      a[6] = (_Float16)w1.z; a[7] = (_Float16)w1.w;
      A[g][ks] = a;
    }

  // ---- per-lane hidden biases for owned units
  f4 bhv[3];
#pragma unroll
  for (int g = 0; g < 3; ++g) bhv[g] = *(const f4*)&bh[g * 768 + j0l];

  // ---- fp32 h master (4 owned (j,b) values)
  f4 hm;
  if (step0 == 0) { hm[0] = 0.f; hm[1] = 0.f; hm[2] = 0.f; hm[3] = 0.f; }
  else hm = *(const f4*)&hfd[(size_t)bglob * 768 + j0l];

  for (int t = 0; t < nsteps; ++t) {
    const int sg = step0 + t;
    const int pin = sg & 1, pout = pin ^ 1;
    const _Float16* __restrict__ hin = hxd + (size_t)pin * 64 * 768;

    // B-fragments: element e -> h[k=ks*32+lh*8+e][b=bglob]  (hx stored [b][k])
    h8 Bf[24];
#pragma unroll
    for (int ks = 0; ks < 24; ++ks)
      Bf[ks] = *(const h8*)&hin[(size_t)bglob * 768 + ks * 32 + lh * 8];

    f4 Cr, Cz, Cn;
    Cr[0]=0.f;Cr[1]=0.f;Cr[2]=0.f;Cr[3]=0.f;
    Cz = Cr; Cn = Cr;
#pragma unroll
    for (int ks = 0; ks < 24; ++ks) {
      Cr = __builtin_amdgcn_mfma_f32_16x16x32_f16(A[0][ks], Bf[ks], Cr, 0, 0, 0);
      Cz = __builtin_amdgcn_mfma_f32_16x16x32_f16(A[1][ks], Bf[ks], Cz, 0, 0, 0);
      Cn = __builtin_amdgcn_mfma_f32_16x16x32_f16(A[2][ks], Bf[ks], Cn, 0, 0, 0);
    }

    // xg: [((lsl*3+gate)*64 + b)*768 + j]
    const int lsl = dir ? (nsteps - 1 - t) : t;
    const _Float16* xrow = xg + (((size_t)lsl * 3) * 64 + bglob) * 768 + j0l;
    h4 xr4 = *(const h4*)xrow;
    h4 xz4 = *(const h4*)(xrow + (size_t)64 * 768);
    h4 xn4 = *(const h4*)(xrow + (size_t)2 * 64 * 768);

    f4 hnew;
    h4 st;
#pragma unroll
    for (int r = 0; r < 4; ++r) {
      float rr = 1.f / (1.f + __expf(-((float)xr4[r] + Cr[r] + bhv[0][r])));
      float zz = 1.f / (1.f + __expf(-((float)xz4[r] + Cz[r] + bhv[1][r])));
      float nn = tanhf((float)xn4[r] + rr * (Cn[r] + bhv[2][r]));
      hnew[r] = (1.f - zz) * nn + zz * hm[r];
      st[r] = (_Float16)hnew[r];
    }
    hm = hnew;
    *(h4*)&hxd[((size_t)pout * 64 + bglob) * 768 + j0l] = st;

    __syncthreads();                       // drains vmcnt before barrier
    if (tid == 0) {
      __threadfence();                     // release h writes (agent scope)
      atomicAdd(&bar[sg], 1u);
      while (__hip_atomic_load(&bar[sg], __ATOMIC_RELAXED, __HIP_MEMORY_SCOPE_AGENT) < 12u) { }
      __threadfence();                     // acquire side
    }
    __syncthreads();
  }

  // save h (chunk boundary or final) - same lane owns same (j,b) next launch
  *(f4*)&hfd[(size_t)bglob * 768 + j0l] = hm;
}

// ---------------------------------------------------------------------------
// MLP head.  hfin layout: [dir][b][j] fp32.
// ---------------------------------------------------------------------------
__global__ __launch_bounds__(256) void mlp1_kernel(
    const float* __restrict__ hfin, const float* __restrict__ W1,
    const float* __restrict__ b1, float* __restrict__ hid)
{
  const int c = blockIdx.x * 4 + (threadIdx.x >> 6);
  const int b = threadIdx.x & 63;
  const float* __restrict__ hf = hfin + (size_t)b * 768;
  const float* __restrict__ hb = hfin + (size_t)(64 + b) * 768;
  const float* __restrict__ w = W1 + (size_t)c * 1536;
  float acc = b1[c];
  for (int k = 0; k < 768; k += 4) {
    float4 hv = *(const float4*)&hf[k];
    float4 wv = *(const float4*)&w[k];
    acc += hv.x * wv.x + hv.y * wv.y + hv.z * wv.z + hv.w * wv.w;
  }
  for (int k = 0; k < 768; k += 4) {
    float4 hv = *(const float4*)&hb[k];
    float4 wv = *(const float4*)&w[768 + k];
    acc += hv.x * wv.x + hv.y * wv.y + hv.z * wv.z + hv.w * wv.w;
  }
  hid[(size_t)c * 64 + b] = fmaxf(acc, 0.f);
}

__global__ void mlp2_kernel(const float* __restrict__ hid,
                            const float* __restrict__ W2,
                            const float* __restrict__ b2,
                            float* __restrict__ out)
{
  const int tid = threadIdx.x;      // 128 threads
  const int b = tid & 63, cls = tid >> 6;
  const float* __restrict__ w = W2 + cls * 768;
  float acc = b2[cls];
  for (int k = 0; k < 768; ++k) acc += hid[(size_t)k * 64 + b] * w[k];
  out[b * 2 + cls] = acc;
}

// ---------------------------------------------------------------------------
extern "C" void kernel_launch(void* const* d_in, const int* in_sizes, int n_in,
                              void* d_out, int out_size, void* d_ws, size_t ws_size,
                              hipStream_t stream)
{
  const int*   ids  = (const int*)d_in[0];
  const float* emb  = (const float*)d_in[1];
  const float* Wi_f = (const float*)d_in[2];
  const float* Wh_f = (const float*)d_in[3];
  const float* bi_f = (const float*)d_in[4];
  const float* bh_f = (const float*)d_in[5];
  const float* Wi_b = (const float*)d_in[6];
  const float* Wh_b = (const float*)d_in[7];
  const float* bi_b = (const float*)d_in[8];
  const float* bh_b = (const float*)d_in[9];
  const float* W1   = (const float*)d_in[10];
  const float* b1   = (const float*)d_in[11];
  const float* W2   = (const float*)d_in[12];
  const float* b2   = (const float*)d_in[13];
  float* out = (float*)d_out;

  // state sizes (elements)
  const size_t N_HX   = (size_t)2 * 2 * 64 * 768;   // halves
  const size_t N_HFIN = (size_t)2 * 64 * 768;       // floats
  const size_t N_HID  = (size_t)HID * BATCH;        // floats
  const size_t N_BAR  = 8 * 512;                    // uints
  const size_t state_bytes = N_HX * 2 + N_HFIN * 4 + N_HID * 4 + N_BAR * 4;

  // choose chunk size: largest CH with 2*CH*64*2304 fp16 xg + state <= ws
  int CH = 512;
  while (CH > 8) {
    size_t need = (size_t)4 * CH * 64 * 2304 + state_bytes;
    if (need <= ws_size) break;
    CH >>= 1;
  }
  const size_t SZ_XG = (size_t)CH * 64 * 2304;      // halves per direction

  char* ws = (char*)d_ws;
  _Float16* xg_f = (_Float16*)ws;
  _Float16* xg_b = xg_f + SZ_XG;
  _Float16* hx   = xg_b + SZ_XG;
  float*    hfin = (float*)(hx + N_HX);
  float*    hid  = hfin + N_HFIN;
  unsigned* bars = (unsigned*)(hid + N_HID);

  // zero hx + hfin + hid + barriers (contiguous region) every launch
  size_t zbytes = N_HX * 2 + N_HFIN * 4 + N_HID * 4 + N_BAR * 4;
  (void)hipMemsetAsync(hx, 0, zbytes, stream);

  const int nch = 512 / CH;
  for (int c = 0; c < nch; ++c) {
    const int s0f = c * CH;                 // fwd window start
    const int s0b = 512 - (c + 1) * CH;     // bwd window start
    gemm1_kernel<<<dim3(CH / 2, 36), 256, 0, stream>>>(
        ids, emb, Wi_f, bi_f, Wi_b, bi_b, s0f, s0b, xg_f, xg_b);
    scan_mfma_kernel<<<96, 256, 0, stream>>>(
        Wh_f, bh_f, Wh_b, bh_b, xg_f, xg_b, hx, hfin, bars, c * CH, CH);
  }
  mlp1_kernel<<<192, 256, 0, stream>>>(hfin, W1, b1, hid);
  mlp2_kernel<<<1, 128, 0, stream>>>(hid, W2, b2, out);
}

// Round 6
// 6795.736 us; speedup vs baseline: 3.2365x; 1.0517x over previous
//
#include <hip/hip_runtime.h>
#include <hip/hip_bf16.h>
#include <cstdint>

typedef _Float16 h2 __attribute__((ext_vector_type(2)));
typedef _Float16 h4 __attribute__((ext_vector_type(4)));
typedef _Float16 h8 __attribute__((ext_vector_type(8)));
typedef float f4 __attribute__((ext_vector_type(4)));
typedef unsigned long long u64;

#define S_LEN 512
#define BATCH 64
#define DM    512
#define HID   768

static __device__ __forceinline__ h2 mk2f(float a, float b) {
  h2 t; t.x = (_Float16)a; t.y = (_Float16)b; return t;
}

union h4u { u64 u; h4 v; };
union h8u { u64 u[2]; h8 v; };

// ---------------------------------------------------------------------------
// Kernel A: xg[dir] = gather(emb, ids) @ Wi^T + bi   (fp32 in, fp16 out)
// Chunked: covers CH sequence steps per direction, starting at s0_f / s0_b.
// Output layout (chunk-local sl): xg[((sl*3 + gate)*64 + b)*768 + j]
// ---------------------------------------------------------------------------
__global__ __launch_bounds__(256) void gemm1_kernel(
    const int* __restrict__ ids, const float* __restrict__ emb,
    const float* __restrict__ Wi_f, const float* __restrict__ bi_f,
    const float* __restrict__ Wi_b, const float* __restrict__ bi_b,
    int s0_f, int s0_b,
    _Float16* __restrict__ xg_f, _Float16* __restrict__ xg_b)
{
  const int mt  = blockIdx.x;      // 0..CH/2-1  (local M tiles of 128)
  const int nty = blockIdx.y;      // 0..35
  const int dir = nty / 18;
  const int nt  = nty - dir * 18;  // 0..17   (N = 2304 / 128)
  const float* __restrict__ Wi = dir ? Wi_b : Wi_f;
  const float* __restrict__ bi = dir ? bi_b : bi_f;
  _Float16*   __restrict__ xg  = dir ? xg_b : xg_f;
  const int s0 = dir ? s0_b : s0_f;

  __shared__ int ids_s[128];
  __shared__ _Float16 As[128][38];   // row stride 38 halves -> conflict-light
  __shared__ _Float16 Bs[128][38];

  const int tid = threadIdx.x;
  if (tid < 128) {
    int m = mt * 128 + tid;          // local m = sl*64 + b
    ids_s[tid] = ids[(m & 63) * S_LEN + s0 + (m >> 6)];   // ids[b][s0+sl]
  }

  float acc[8][8];
#pragma unroll
  for (int i = 0; i < 8; ++i)
#pragma unroll
    for (int j = 0; j < 8; ++j) acc[i][j] = 0.f;

  const int tr = tid >> 4, tc = tid & 15;
  const int r0 = tr * 8, c0 = tc * 8;
  const int lr = tid >> 1, lh = tid & 1;

  __syncthreads();

  for (int kt = 0; kt < DM; kt += 32) {
    {
      const float* srcA = emb + (size_t)ids_s[lr] * DM + kt + lh * 16;
      const float* srcB = Wi + (size_t)(nt * 128 + lr) * DM + kt + lh * 16;
      float4 a0 = ((const float4*)srcA)[0], a1 = ((const float4*)srcA)[1];
      float4 a2 = ((const float4*)srcA)[2], a3 = ((const float4*)srcA)[3];
      float4 b0 = ((const float4*)srcB)[0], b1v = ((const float4*)srcB)[1];
      float4 b2v = ((const float4*)srcB)[2], b3 = ((const float4*)srcB)[3];
      h2* da = (h2*)&As[lr][lh * 16];
      h2* db = (h2*)&Bs[lr][lh * 16];
      da[0] = mk2f(a0.x, a0.y);  da[1] = mk2f(a0.z, a0.w);
      da[2] = mk2f(a1.x, a1.y);  da[3] = mk2f(a1.z, a1.w);
      da[4] = mk2f(a2.x, a2.y);  da[5] = mk2f(a2.z, a2.w);
      da[6] = mk2f(a3.x, a3.y);  da[7] = mk2f(a3.z, a3.w);
      db[0] = mk2f(b0.x, b0.y);  db[1] = mk2f(b0.z, b0.w);
      db[2] = mk2f(b1v.x, b1v.y); db[3] = mk2f(b1v.z, b1v.w);
      db[4] = mk2f(b2v.x, b2v.y); db[5] = mk2f(b2v.z, b2v.w);
      db[6] = mk2f(b3.x, b3.y);  db[7] = mk2f(b3.z, b3.w);
    }
    __syncthreads();
#pragma unroll
    for (int kp = 0; kp < 16; ++kp) {
      h2 av[8], bv[8];
#pragma unroll
      for (int i = 0; i < 8; ++i) av[i] = *(const h2*)&As[r0 + i][kp * 2];
#pragma unroll
      for (int j = 0; j < 8; ++j) bv[j] = *(const h2*)&Bs[c0 + j][kp * 2];
#pragma unroll
      for (int i = 0; i < 8; ++i)
#pragma unroll
        for (int j = 0; j < 8; ++j)
          acc[i][j] = __builtin_amdgcn_fdot2(av[i], bv[j], acc[i][j], false);
    }
    __syncthreads();
  }

  float biv[8];
#pragma unroll
  for (int j = 0; j < 8; ++j) biv[j] = bi[nt * 128 + c0 + j];
  const int n0 = nt * 128 + c0;          // 8 consecutive n, same gate (768%8==0)
  const int gate = n0 / 768;
  const int jj = n0 - gate * 768;
#pragma unroll
  for (int i = 0; i < 8; ++i) {
    int m = mt * 128 + r0 + i;
    int sl = m >> 6, b = m & 63;         // chunk-local step, batch
    h8 v;
#pragma unroll
    for (int j = 0; j < 8; ++j) v[j] = (_Float16)(acc[i][j] + biv[j]);
    *(h8*)&xg[(((size_t)sl * 3 + gate) * 64 + b) * 768 + jj] = v;
  }
}

// ---------------------------------------------------------------------------
// Kernel B: MFMA GRU scan, weights register-resident, fence-free exchange.
// 96 blocks x 256 threads, __launch_bounds__(256,1). Block = (dir, bgroup of
// 16, jb twelfth of units). Wave owns 16 units; Wh lives in VGPR/AGPR
// A-fragments. Cross-block h exchange: RELAXED AGENT atomics (coherent sc1
// accesses -> no L2 writeback/invalidate fences). Per-step barrier: per-block
// flag (RELEASE store) + 12 parallel RELAXED spin loads. xg for step t+1
// prefetched before the barrier.
// ---------------------------------------------------------------------------
__global__ __launch_bounds__(256, 1) void scan_mfma_kernel(
    const float* __restrict__ Wh_f, const float* __restrict__ bh_f,
    const float* __restrict__ Wh_b, const float* __restrict__ bh_b,
    const _Float16* __restrict__ xg_f, const _Float16* __restrict__ xg_b,
    _Float16* __restrict__ hx,      // [dir][parity][64][768] fp16
    float* __restrict__ hfin,       // [dir][64][768] fp32 chunk-save / final
    unsigned* __restrict__ flags,   // [8 domains][512 steps][16]
    int step0, int nsteps)
{
  const int blk = blockIdx.x;       // 0..95
  const int dir = blk / 48;
  const int l   = blk - dir * 48;   // 0..47
  const int bg  = l / 12;           // batch group 0..3
  const int jb  = l - bg * 12;      // unit twelfth 0..11
  const int dom = dir * 4 + bg;

  const float* __restrict__ Wh = dir ? Wh_b : Wh_f;
  const float* __restrict__ bh = dir ? bh_b : bh_f;
  const _Float16* __restrict__ xg = dir ? xg_b : xg_f;
  _Float16* __restrict__ hxd = hx + (size_t)dir * 2 * 64 * 768;
  float*    __restrict__ hfd = hfin + (size_t)dir * 64 * 768;

  const int tid = threadIdx.x;
  const int w   = tid >> 6;         // wave 0..3
  const int L   = tid & 63;
  const int lh  = L >> 4;           // 0..3
  const int ln  = L & 15;           // 0..15
  const int jt  = jb * 4 + w;       // unit tile 0..47
  const int jrow = jt * 16 + ln;    // A-fragment row (j)
  const int j0l  = jt * 16 + lh * 4;  // 4 owned units j0l..j0l+3
  const int bglob = bg * 16 + ln;   // owned batch column

  // ---- load Wh as A-fragments: A[gate][ks], element e -> Wh[j=jrow][ks*32+lh*8+e]
  h8 A[3][24];
#pragma unroll
  for (int g = 0; g < 3; ++g)
#pragma unroll
    for (int ks = 0; ks < 24; ++ks) {
      const float* src = Wh + (size_t)(g * 768 + jrow) * 768 + ks * 32 + lh * 8;
      float4 w0 = ((const float4*)src)[0];
      float4 w1 = ((const float4*)src)[1];
      h8 a;
      a[0] = (_Float16)w0.x; a[1] = (_Float16)w0.y;
      a[2] = (_Float16)w0.z; a[3] = (_Float16)w0.w;
      a[4] = (_Float16)w1.x; a[5] = (_Float16)w1.y;
      a[6] = (_Float16)w1.z; a[7] = (_Float16)w1.w;
      A[g][ks] = a;
    }

  // ---- per-lane hidden biases for owned units
  f4 bhv[3];
#pragma unroll
  for (int g = 0; g < 3; ++g) bhv[g] = *(const f4*)&bh[g * 768 + j0l];

  // ---- fp32 h master (4 owned (j,b) values)
  f4 hm;
  if (step0 == 0) { hm[0] = 0.f; hm[1] = 0.f; hm[2] = 0.f; hm[3] = 0.f; }
  else hm = *(const f4*)&hfd[(size_t)bglob * 768 + j0l];

  // xg prologue (step 0 of chunk)
  h4 xr4, xz4, xn4;
  {
    const int lsl = dir ? (nsteps - 1) : 0;
    const _Float16* xrow = xg + (((size_t)lsl * 3) * 64 + bglob) * 768 + j0l;
    xr4 = *(const h4*)xrow;
    xz4 = *(const h4*)(xrow + (size_t)64 * 768);
    xn4 = *(const h4*)(xrow + (size_t)2 * 64 * 768);
  }

  for (int t = 0; t < nsteps; ++t) {
    const int sg = step0 + t;
    const int pin = sg & 1, pout = pin ^ 1;
    const _Float16* __restrict__ hin = hxd + (size_t)pin * 64 * 768;

    // B-fragments via coherent (agent-scope) relaxed atomic loads.
    // element e -> h[k=ks*32+lh*8+e][b=bglob]  (hx stored [b][k])
    u64* hin64 = (u64*)(hin + (size_t)bglob * 768);
    h8 Bf[24];
#pragma unroll
    for (int ks = 0; ks < 24; ++ks) {
      h8u tmp;
      tmp.u[0] = __hip_atomic_load(hin64 + ks * 8 + lh * 2,
                                   __ATOMIC_RELAXED, __HIP_MEMORY_SCOPE_AGENT);
      tmp.u[1] = __hip_atomic_load(hin64 + ks * 8 + lh * 2 + 1,
                                   __ATOMIC_RELAXED, __HIP_MEMORY_SCOPE_AGENT);
      Bf[ks] = tmp.v;
    }

    f4 Cr, Cz, Cn;
    Cr[0]=0.f;Cr[1]=0.f;Cr[2]=0.f;Cr[3]=0.f;
    Cz = Cr; Cn = Cr;
#pragma unroll
    for (int ks = 0; ks < 24; ++ks) {
      Cr = __builtin_amdgcn_mfma_f32_16x16x32_f16(A[0][ks], Bf[ks], Cr, 0, 0, 0);
      Cz = __builtin_amdgcn_mfma_f32_16x16x32_f16(A[1][ks], Bf[ks], Cz, 0, 0, 0);
      Cn = __builtin_amdgcn_mfma_f32_16x16x32_f16(A[2][ks], Bf[ks], Cn, 0, 0, 0);
    }

    f4 hnew;
    h4u st;
#pragma unroll
    for (int r = 0; r < 4; ++r) {
      float rr = 1.f / (1.f + __expf(-((float)xr4[r] + Cr[r] + bhv[0][r])));
      float zz = 1.f / (1.f + __expf(-((float)xz4[r] + Cz[r] + bhv[1][r])));
      float nn = tanhf((float)xn4[r] + rr * (Cn[r] + bhv[2][r]));
      hnew[r] = (1.f - zz) * nn + zz * hm[r];
      st.v[r] = (_Float16)hnew[r];
    }
    hm = hnew;
    __hip_atomic_store((u64*)&hxd[((size_t)pout * 64 + bglob) * 768 + j0l], st.u,
                       __ATOMIC_RELAXED, __HIP_MEMORY_SCOPE_AGENT);

    // prefetch next step's xg (h-independent) so latency hides under barrier
    if (t + 1 < nsteps) {
      const int lsl = dir ? (nsteps - 2 - t) : (t + 1);
      const _Float16* xrow = xg + (((size_t)lsl * 3) * 64 + bglob) * 768 + j0l;
      xr4 = *(const h4*)xrow;
      xz4 = *(const h4*)(xrow + (size_t)64 * 768);
      xn4 = *(const h4*)(xrow + (size_t)2 * 64 * 768);
    }

    __syncthreads();   // drains every wave's h-store (vmcnt) before flag set
    if (w == 0) {
      unsigned* f = flags + ((size_t)dom * 512 + sg) * 16;
      if (L == 0)
        __hip_atomic_store(&f[jb], 1u, __ATOMIC_RELEASE, __HIP_MEMORY_SCOPE_AGENT);
      if (L < 12) {
        while (__hip_atomic_load(&f[L], __ATOMIC_RELAXED,
                                 __HIP_MEMORY_SCOPE_AGENT) == 0u) { }
      }
    }
    asm volatile("" ::: "memory");
    __syncthreads();
  }

  // save h (chunk boundary or final) - same lane owns same (j,b) next launch
  *(f4*)&hfd[(size_t)bglob * 768 + j0l] = hm;
}

// ---------------------------------------------------------------------------
// MLP head.  hfin layout: [dir][b][j] fp32.
// ---------------------------------------------------------------------------
__global__ __launch_bounds__(256) void mlp1_kernel(
    const float* __restrict__ hfin, const float* __restrict__ W1,
    const float* __restrict__ b1, float* __restrict__ hid)
{
  const int c = blockIdx.x * 4 + (threadIdx.x >> 6);
  const int b = threadIdx.x & 63;
  const float* __restrict__ hf = hfin + (size_t)b * 768;
  const float* __restrict__ hb = hfin + (size_t)(64 + b) * 768;
  const float* __restrict__ w = W1 + (size_t)c * 1536;
  float acc = b1[c];
  for (int k = 0; k < 768; k += 4) {
    float4 hv = *(const float4*)&hf[k];
    float4 wv = *(const float4*)&w[k];
    acc += hv.x * wv.x + hv.y * wv.y + hv.z * wv.z + hv.w * wv.w;
  }
  for (int k = 0; k < 768; k += 4) {
    float4 hv = *(const float4*)&hb[k];
    float4 wv = *(const float4*)&w[768 + k];
    acc += hv.x * wv.x + hv.y * wv.y + hv.z * wv.z + hv.w * wv.w;
  }
  hid[(size_t)c * 64 + b] = fmaxf(acc, 0.f);
}

__global__ void mlp2_kernel(const float* __restrict__ hid,
                            const float* __restrict__ W2,
                            const float* __restrict__ b2,
                            float* __restrict__ out)
{
  const int tid = threadIdx.x;      // 128 threads
  const int b = tid & 63, cls = tid >> 6;
  const float* __restrict__ w = W2 + cls * 768;
  float acc = b2[cls];
  for (int k = 0; k < 768; ++k) acc += hid[(size_t)k * 64 + b] * w[k];
  out[b * 2 + cls] = acc;
}

// ---------------------------------------------------------------------------
extern "C" void kernel_launch(void* const* d_in, const int* in_sizes, int n_in,
                              void* d_out, int out_size, void* d_ws, size_t ws_size,
                              hipStream_t stream)
{
  const int*   ids  = (const int*)d_in[0];
  const float* emb  = (const float*)d_in[1];
  const float* Wi_f = (const float*)d_in[2];
  const float* Wh_f = (const float*)d_in[3];
  const float* bi_f = (const float*)d_in[4];
  const float* bh_f = (const float*)d_in[5];
  const float* Wi_b = (const float*)d_in[6];
  const float* Wh_b = (const float*)d_in[7];
  const float* bi_b = (const float*)d_in[8];
  const float* bh_b = (const float*)d_in[9];
  const float* W1   = (const float*)d_in[10];
  const float* b1   = (const float*)d_in[11];
  const float* W2   = (const float*)d_in[12];
  const float* b2   = (const float*)d_in[13];
  float* out = (float*)d_out;

  // state sizes (elements)
  const size_t N_HX   = (size_t)2 * 2 * 64 * 768;   // halves
  const size_t N_HFIN = (size_t)2 * 64 * 768;       // floats
  const size_t N_HID  = (size_t)HID * BATCH;        // floats
  const size_t N_FLG  = (size_t)8 * 512 * 16;       // uints
  const size_t state_bytes = N_HX * 2 + N_HFIN * 4 + N_HID * 4 + N_FLG * 4;

  // choose chunk size: largest CH with 2*CH*64*2304 fp16 xg + state <= ws
  int CH = 512;
  while (CH > 8) {
    size_t need = (size_t)4 * CH * 64 * 2304 + state_bytes;
    if (need <= ws_size) break;
    CH >>= 1;
  }
  const size_t SZ_XG = (size_t)CH * 64 * 2304;      // halves per direction

  char* ws = (char*)d_ws;
  _Float16* xg_f = (_Float16*)ws;
  _Float16* xg_b = xg_f + SZ_XG;
  _Float16* hx   = xg_b + SZ_XG;
  float*    hfin = (float*)(hx + N_HX);
  float*    hid  = hfin + N_HFIN;
  unsigned* flags = (unsigned*)(hid + N_HID);

  // zero hx + hfin + hid + flags (contiguous region) every launch
  size_t zbytes = N_HX * 2 + N_HFIN * 4 + N_HID * 4 + N_FLG * 4;
  (void)hipMemsetAsync(hx, 0, zbytes, stream);

  const int nch = 512 / CH;
  for (int c = 0; c < nch; ++c) {
    const int s0f = c * CH;                 // fwd window start
    const int s0b = 512 - (c + 1) * CH;     // bwd window start
    gemm1_kernel<<<dim3(CH / 2, 36), 256, 0, stream>>>(
        ids, emb, Wi_f, bi_f, Wi_b, bi_b, s0f, s0b, xg_f, xg_b);
    scan_mfma_kernel<<<96, 256, 0, stream>>>(
        Wh_f, bh_f, Wh_b, bh_b, xg_f, xg_b, hx, hfin, flags, c * CH, CH);
  }
  mlp1_kernel<<<192, 256, 0, stream>>>(hfin, W1, b1, hid);
  mlp2_kernel<<<1, 128, 0, stream>>>(hid, W2, b2, out);
}

// Round 8
// 3799.302 us; speedup vs baseline: 5.7891x; 1.7887x over previous
//
#include <hip/hip_runtime.h>
#include <hip/hip_bf16.h>
#include <cstdint>

typedef _Float16 h2 __attribute__((ext_vector_type(2)));
typedef _Float16 h4 __attribute__((ext_vector_type(4)));
typedef _Float16 h8 __attribute__((ext_vector_type(8)));
typedef float f4 __attribute__((ext_vector_type(4)));
typedef unsigned int u32x4 __attribute__((ext_vector_type(4)));
typedef unsigned long long u64;

#define S_LEN 512
#define BATCH 64
#define DM    512
#define HID   768

static __device__ __forceinline__ h2 mk2f(float a, float b) {
  h2 t; t.x = (_Float16)a; t.y = (_Float16)b; return t;
}

union h4u { u64 u; h4 v; };

// ---------------------------------------------------------------------------
// Kernel A: xg[dir] = gather(emb, ids) @ Wi^T + bi   (fp32 in, fp16 out)
// Chunked: covers CH sequence steps per direction, starting at s0_f / s0_b.
// Output layout (chunk-local sl): xg[((sl*3 + gate)*64 + b)*768 + j]
// ---------------------------------------------------------------------------
__global__ __launch_bounds__(256) void gemm1_kernel(
    const int* __restrict__ ids, const float* __restrict__ emb,
    const float* __restrict__ Wi_f, const float* __restrict__ bi_f,
    const float* __restrict__ Wi_b, const float* __restrict__ bi_b,
    int s0_f, int s0_b,
    _Float16* __restrict__ xg_f, _Float16* __restrict__ xg_b)
{
  const int mt  = blockIdx.x;      // 0..CH/2-1  (local M tiles of 128)
  const int nty = blockIdx.y;      // 0..35
  const int dir = nty / 18;
  const int nt  = nty - dir * 18;  // 0..17   (N = 2304 / 128)
  const float* __restrict__ Wi = dir ? Wi_b : Wi_f;
  const float* __restrict__ bi = dir ? bi_b : bi_f;
  _Float16*   __restrict__ xg  = dir ? xg_b : xg_f;
  const int s0 = dir ? s0_b : s0_f;

  __shared__ int ids_s[128];
  __shared__ _Float16 As[128][38];   // row stride 38 halves -> conflict-light
  __shared__ _Float16 Bs[128][38];

  const int tid = threadIdx.x;
  if (tid < 128) {
    int m = mt * 128 + tid;          // local m = sl*64 + b
    ids_s[tid] = ids[(m & 63) * S_LEN + s0 + (m >> 6)];   // ids[b][s0+sl]
  }

  float acc[8][8];
#pragma unroll
  for (int i = 0; i < 8; ++i)
#pragma unroll
    for (int j = 0; j < 8; ++j) acc[i][j] = 0.f;

  const int tr = tid >> 4, tc = tid & 15;
  const int r0 = tr * 8, c0 = tc * 8;
  const int lr = tid >> 1, lh = tid & 1;

  __syncthreads();

  for (int kt = 0; kt < DM; kt += 32) {
    {
      const float* srcA = emb + (size_t)ids_s[lr] * DM + kt + lh * 16;
      const float* srcB = Wi + (size_t)(nt * 128 + lr) * DM + kt + lh * 16;
      float4 a0 = ((const float4*)srcA)[0], a1 = ((const float4*)srcA)[1];
      float4 a2 = ((const float4*)srcA)[2], a3 = ((const float4*)srcA)[3];
      float4 b0 = ((const float4*)srcB)[0], b1v = ((const float4*)srcB)[1];
      float4 b2v = ((const float4*)srcB)[2], b3 = ((const float4*)srcB)[3];
      h2* da = (h2*)&As[lr][lh * 16];
      h2* db = (h2*)&Bs[lr][lh * 16];
      da[0] = mk2f(a0.x, a0.y);  da[1] = mk2f(a0.z, a0.w);
      da[2] = mk2f(a1.x, a1.y);  da[3] = mk2f(a1.z, a1.w);
      da[4] = mk2f(a2.x, a2.y);  da[5] = mk2f(a2.z, a2.w);
      da[6] = mk2f(a3.x, a3.y);  da[7] = mk2f(a3.z, a3.w);
      db[0] = mk2f(b0.x, b0.y);  db[1] = mk2f(b0.z, b0.w);
      db[2] = mk2f(b1v.x, b1v.y); db[3] = mk2f(b1v.z, b1v.w);
      db[4] = mk2f(b2v.x, b2v.y); db[5] = mk2f(b2v.z, b2v.w);
      db[6] = mk2f(b3.x, b3.y);  db[7] = mk2f(b3.z, b3.w);
    }
    __syncthreads();
#pragma unroll
    for (int kp = 0; kp < 16; ++kp) {
      h2 av[8], bv[8];
#pragma unroll
      for (int i = 0; i < 8; ++i) av[i] = *(const h2*)&As[r0 + i][kp * 2];
#pragma unroll
      for (int j = 0; j < 8; ++j) bv[j] = *(const h2*)&Bs[c0 + j][kp * 2];
#pragma unroll
      for (int i = 0; i < 8; ++i)
#pragma unroll
        for (int j = 0; j < 8; ++j)
          acc[i][j] = __builtin_amdgcn_fdot2(av[i], bv[j], acc[i][j], false);
    }
    __syncthreads();
  }

  float biv[8];
#pragma unroll
  for (int j = 0; j < 8; ++j) biv[j] = bi[nt * 128 + c0 + j];
  const int n0 = nt * 128 + c0;          // 8 consecutive n, same gate (768%8==0)
  const int gate = n0 / 768;
  const int jj = n0 - gate * 768;
#pragma unroll
  for (int i = 0; i < 8; ++i) {
    int m = mt * 128 + r0 + i;
    int sl = m >> 6, b = m & 63;         // chunk-local step, batch
    h8 v;
#pragma unroll
    for (int j = 0; j < 8; ++j) v[j] = (_Float16)(acc[i][j] + biv[j]);
    *(h8*)&xg[(((size_t)sl * 3 + gate) * 64 + b) * 768 + jj] = v;
  }
}

// ---------------------------------------------------------------------------
// Kernel B: MFMA GRU scan. 96 blocks x 256 threads, weights in VGPR/AGPR.
// Protocol (placement-independent, no barriers, no release/acquire):
//  - payload: hx[dir][parity][b][g]  (16B granule = 8 fp16, k-major groups)
//  - tags:    tags[dir][b][16] u32, monotonically = last stored step+1
//  - producer: store payload (sc0 sc1), vmcnt(0), __syncthreads,
//              lanes 0..15 store tag (sc0 sc1)
//  - consumer: spin on 12 tags >= sg, then load payload (proven complete),
//              stage to LDS [g][b] (conflict-free ds_read_b128), MFMA.
// ---------------------------------------------------------------------------
__global__ __launch_bounds__(256, 1) void scan_mfma_kernel(
    const float* __restrict__ Wh_f, const float* __restrict__ bh_f,
    const float* __restrict__ Wh_b, const float* __restrict__ bh_b,
    const _Float16* __restrict__ xg_f, const _Float16* __restrict__ xg_b,
    char* __restrict__ hx,          // payload: 2*2*64*96*16 bytes
    unsigned* __restrict__ tags,    // 2*64*16 u32
    float* __restrict__ hfin,       // [dir][64][768] fp32 chunk-save
    int step0, int nsteps)
{
  const int blk = blockIdx.x;       // 0..95
  const int dir = blk / 48;
  const int l   = blk - dir * 48;   // 0..47
  const int bg  = l / 12;           // batch group 0..3
  const int jb  = l - bg * 12;      // unit twelfth 0..11

  const float* __restrict__ Wh = dir ? Wh_b : Wh_f;
  const float* __restrict__ bh = dir ? bh_b : bh_f;
  const _Float16* __restrict__ xg = dir ? xg_b : xg_f;
  char*     payB = hx + (size_t)dir * 2 * 64 * 96 * 16;
  unsigned* tagB = tags + dir * 64 * 16;
  float*    hfd  = hfin + (size_t)dir * 64 * 768;

  const int tid = threadIdx.x;
  const int w   = tid >> 6;         // wave 0..3
  const int L   = tid & 63;
  const int lh  = L >> 4;           // 0..3
  const int ln  = L & 15;           // 0..15
  const int jt  = jb * 4 + w;       // unit tile 0..47
  const int jrow = jt * 16 + ln;    // A-fragment row (j)
  const int j0l  = jt * 16 + lh * 4;  // 4 owned units
  const int bglob = bg * 16 + ln;   // owned batch column (producer)
  const int bb  = tid >> 4;         // consumer batch row 0..15
  const int qi  = tid & 15;         // consumer granule base

  __shared__ __align__(16) unsigned char hs[96 * 256];  // [g][16 b][16B] 24KB

  // ---- Wh as A-fragments: A[gate][ks] elem e -> Wh[jrow][ks*32+lh*8+e]
  h8 A[3][24];
#pragma unroll
  for (int g = 0; g < 3; ++g)
#pragma unroll
    for (int ks = 0; ks < 24; ++ks) {
      const float* src = Wh + (size_t)(g * 768 + jrow) * 768 + ks * 32 + lh * 8;
      float4 w0 = ((const float4*)src)[0];
      float4 w1 = ((const float4*)src)[1];
      h8 a;
      a[0] = (_Float16)w0.x; a[1] = (_Float16)w0.y;
      a[2] = (_Float16)w0.z; a[3] = (_Float16)w0.w;
      a[4] = (_Float16)w1.x; a[5] = (_Float16)w1.y;
      a[6] = (_Float16)w1.z; a[7] = (_Float16)w1.w;
      A[g][ks] = a;
    }

  f4 bhv[3];
#pragma unroll
  for (int g = 0; g < 3; ++g) bhv[g] = *(const f4*)&bh[g * 768 + j0l];

  // ---- fp32 h master
  f4 hm;
  if (step0 == 0) { hm[0]=0.f; hm[1]=0.f; hm[2]=0.f; hm[3]=0.f; }
  else {
    const float* src = &hfd[(size_t)bglob * 768 + j0l];
    asm volatile("global_load_dwordx4 %0, %1, off sc0 sc1\n\t"
                 "s_waitcnt vmcnt(0)"
                 : "=&v"(hm) : "v"(src) : "memory");
  }

  unsigned* mytag = tagB + (bg * 16 + bb) * 16;          // consumer's 12 tags
  const char* pcb = payB;                                 // payload base
  // producer payload slot: granule jt*2+(lh>>1), half lh&1
  const size_t pslot = ((size_t)bglob * 96 + jt * 2 + (lh >> 1)) * 16
                     + (size_t)(lh & 1) * 8;

  for (int t = 0; t < nsteps; ++t) {
    const int sg = step0 + t;
    const int pin = sg & 1, pout = pin ^ 1;

    // xg loads for this step (plain cached; overlap the spin)
    const int lsl = dir ? (nsteps - 1 - t) : t;
    const _Float16* xrow = xg + (((size_t)lsl * 3) * 64 + bglob) * 768 + j0l;
    h4 xr4 = *(const h4*)xrow;
    h4 xz4 = *(const h4*)(xrow + (size_t)64 * 768);
    h4 xn4 = *(const h4*)(xrow + (size_t)2 * 64 * 768);

    // ---- tag spin: all 12 producer tags for batch (bg*16+bb) >= sg
    {
      u32x4 t0, t1, t2;
      for (;;) {
        asm volatile(
          "global_load_dwordx4 %0, %3, off sc0 sc1\n\t"
          "global_load_dwordx4 %1, %4, off sc0 sc1\n\t"
          "global_load_dwordx4 %2, %5, off sc0 sc1\n\t"
          "s_waitcnt vmcnt(0)"
          : "=&v"(t0), "=&v"(t1), "=&v"(t2)
          : "v"(mytag), "v"(mytag + 4), "v"(mytag + 8)
          : "memory");
        unsigned m01 = min(min(t0[0], t0[1]), min(t0[2], t0[3]));
        unsigned m23 = min(min(t1[0], t1[1]), min(t1[2], t1[3]));
        unsigned m45 = min(min(t2[0], t2[1]), min(t2[2], t2[3]));
        if (min(min(m01, m23), m45) >= (unsigned)sg) break;
      }
    }

    // ---- payload: 6 granules of 16B for batch bb (proven complete)
    u32x4 p0, p1, p2, p3, p4, p5;
    {
      const char* pc = pcb + (((size_t)pin * 64 + bg * 16 + bb) * 96 + qi) * 16;
      asm volatile(
        "global_load_dwordx4 %0, %6, off sc0 sc1\n\t"
        "global_load_dwordx4 %1, %7, off sc0 sc1\n\t"
        "global_load_dwordx4 %2, %8, off sc0 sc1\n\t"
        "global_load_dwordx4 %3, %9, off sc0 sc1\n\t"
        "global_load_dwordx4 %4, %10, off sc0 sc1\n\t"
        "global_load_dwordx4 %5, %11, off sc0 sc1\n\t"
        "s_waitcnt vmcnt(0)"
        : "=&v"(p0), "=&v"(p1), "=&v"(p2), "=&v"(p3), "=&v"(p4), "=&v"(p5)
        : "v"(pc), "v"(pc + 16*16), "v"(pc + 32*16), "v"(pc + 48*16),
          "v"(pc + 64*16), "v"(pc + 80*16)
        : "memory");
    }

    // ---- stage to LDS [g][bb] (previous step's readers passed last sync)
    *(u32x4*)(hs + (qi +  0) * 256 + bb * 16) = p0;
    *(u32x4*)(hs + (qi + 16) * 256 + bb * 16) = p1;
    *(u32x4*)(hs + (qi + 32) * 256 + bb * 16) = p2;
    *(u32x4*)(hs + (qi + 48) * 256 + bb * 16) = p3;
    *(u32x4*)(hs + (qi + 64) * 256 + bb * 16) = p4;
    *(u32x4*)(hs + (qi + 80) * 256 + bb * 16) = p5;
    __syncthreads();

    // ---- B-fragments from LDS + MFMA
    f4 Cr, Cz, Cn;
    Cr[0]=0.f;Cr[1]=0.f;Cr[2]=0.f;Cr[3]=0.f;
    Cz = Cr; Cn = Cr;
#pragma unroll
    for (int ks = 0; ks < 24; ++ks) {
      h8 Bf = *(const h8*)(hs + (ks * 4 + lh) * 256 + ln * 16);
      Cr = __builtin_amdgcn_mfma_f32_16x16x32_f16(A[0][ks], Bf, Cr, 0, 0, 0);
      Cz = __builtin_amdgcn_mfma_f32_16x16x32_f16(A[1][ks], Bf, Cz, 0, 0, 0);
      Cn = __builtin_amdgcn_mfma_f32_16x16x32_f16(A[2][ks], Bf, Cn, 0, 0, 0);
    }

    // ---- gates
    f4 hnew;
    h4u st;
#pragma unroll
    for (int r = 0; r < 4; ++r) {
      float rr = 1.f / (1.f + __expf(-((float)xr4[r] + Cr[r] + bhv[0][r])));
      float zz = 1.f / (1.f + __expf(-((float)xz4[r] + Cz[r] + bhv[1][r])));
      float nn = tanhf((float)xn4[r] + rr * (Cn[r] + bhv[2][r]));
      hnew[r] = (1.f - zz) * nn + zz * hm[r];
      st.v[r] = (_Float16)hnew[r];
    }
    hm = hnew;

    // ---- producer: payload store, drain, block-sync, tag store
    {
      char* dst = payB + (size_t)pout * 64 * 96 * 16 + pslot;
      asm volatile("global_store_dwordx2 %0, %1, off sc0 sc1"
                   :: "v"(dst), "v"(st.u) : "memory");
      asm volatile("s_waitcnt vmcnt(0)" ::: "memory");
    }
    __syncthreads();
    if (tid < 16) {
      unsigned tv = (unsigned)(sg + 1);
      unsigned* ta = tagB + (bg * 16 + tid) * 16 + jb;
      asm volatile("global_store_dword %0, %1, off sc0 sc1"
                   :: "v"(ta), "v"(tv) : "memory");
    }
  }

  // chunk-save fp32 h (read by next launch's same lane, sc0 sc1 both sides)
  {
    float* dst = &hfd[(size_t)bglob * 768 + j0l];
    asm volatile("global_store_dwordx4 %0, %1, off sc0 sc1"
                 :: "v"(dst), "v"(hm) : "memory");
  }
}

// ---------------------------------------------------------------------------
// MLP head.  hfin layout: [dir][b][j] fp32.
// ---------------------------------------------------------------------------
__global__ __launch_bounds__(256) void mlp1_kernel(
    const float* __restrict__ hfin, const float* __restrict__ W1,
    const float* __restrict__ b1, float* __restrict__ hid)
{
  const int c = blockIdx.x * 4 + (threadIdx.x >> 6);
  const int b = threadIdx.x & 63;
  const float* __restrict__ hf = hfin + (size_t)b * 768;
  const float* __restrict__ hb = hfin + (size_t)(64 + b) * 768;
  const float* __restrict__ w = W1 + (size_t)c * 1536;
  float acc = b1[c];
  for (int k = 0; k < 768; k += 4) {
    float4 hv = *(const float4*)&hf[k];
    float4 wv = *(const float4*)&w[k];
    acc += hv.x * wv.x + hv.y * wv.y + hv.z * wv.z + hv.w * wv.w;
  }
  for (int k = 0; k < 768; k += 4) {
    float4 hv = *(const float4*)&hb[k];
    float4 wv = *(const float4*)&w[768 + k];
    acc += hv.x * wv.x + hv.y * wv.y + hv.z * wv.z + hv.w * wv.w;
  }
  hid[(size_t)c * 64 + b] = fmaxf(acc, 0.f);
}

__global__ void mlp2_kernel(const float* __restrict__ hid,
                            const float* __restrict__ W2,
                            const float* __restrict__ b2,
                            float* __restrict__ out)
{
  const int tid = threadIdx.x;      // 128 threads
  const int b = tid & 63, cls = tid >> 6;
  const float* __restrict__ w = W2 + cls * 768;
  float acc = b2[cls];
  for (int k = 0; k < 768; ++k) acc += hid[(size_t)k * 64 + b] * w[k];
  out[b * 2 + cls] = acc;
}

// ---------------------------------------------------------------------------
extern "C" void kernel_launch(void* const* d_in, const int* in_sizes, int n_in,
                              void* d_out, int out_size, void* d_ws, size_t ws_size,
                              hipStream_t stream)
{
  const int*   ids  = (const int*)d_in[0];
  const float* emb  = (const float*)d_in[1];
  const float* Wi_f = (const float*)d_in[2];
  const float* Wh_f = (const float*)d_in[3];
  const float* bi_f = (const float*)d_in[4];
  const float* bh_f = (const float*)d_in[5];
  const float* Wi_b = (const float*)d_in[6];
  const float* Wh_b = (const float*)d_in[7];
  const float* bi_b = (const float*)d_in[8];
  const float* bh_b = (const float*)d_in[9];
  const float* W1   = (const float*)d_in[10];
  const float* b1   = (const float*)d_in[11];
  const float* W2   = (const float*)d_in[12];
  const float* b2   = (const float*)d_in[13];
  float* out = (float*)d_out;

  // state sizes (bytes)
  const size_t B_HX   = (size_t)2 * 2 * 64 * 96 * 16;   // 393216
  const size_t B_TAG  = (size_t)2 * 64 * 16 * 4;        // 8192
  const size_t B_HFIN = (size_t)2 * 64 * 768 * 4;       // 393216
  const size_t B_HID  = (size_t)HID * BATCH * 4;        // 196608
  const size_t state_bytes = B_HX + B_TAG + B_HFIN + B_HID;

  // choose chunk size: largest CH with 2*CH*64*2304 fp16 xg + state <= ws
  int CH = 512;
  while (CH > 8) {
    size_t need = (size_t)4 * CH * 64 * 2304 + state_bytes;
    if (need <= ws_size) break;
    CH >>= 1;
  }
  const size_t SZ_XG = (size_t)CH * 64 * 2304;          // halves per direction

  char* ws = (char*)d_ws;
  _Float16* xg_f = (_Float16*)ws;
  _Float16* xg_b = xg_f + SZ_XG;
  char*     hx   = (char*)(xg_b + SZ_XG);
  unsigned* tags = (unsigned*)(hx + B_HX);
  float*    hfin = (float*)((char*)tags + B_TAG);
  float*    hid  = (float*)((char*)hfin + B_HFIN);

  // zero hx + tags + hfin + hid (contiguous) every call
  (void)hipMemsetAsync(hx, 0, state_bytes, stream);

  const int nch = 512 / CH;
  for (int c = 0; c < nch; ++c) {
    const int s0f = c * CH;                 // fwd window start
    const int s0b = 512 - (c + 1) * CH;     // bwd window start
    gemm1_kernel<<<dim3(CH / 2, 36), 256, 0, stream>>>(
        ids, emb, Wi_f, bi_f, Wi_b, bi_b, s0f, s0b, xg_f, xg_b);
    scan_mfma_kernel<<<96, 256, 0, stream>>>(
        Wh_f, bh_f, Wh_b, bh_b, xg_f, xg_b, hx, tags, hfin, c * CH, CH);
  }
  mlp1_kernel<<<192, 256, 0, stream>>>(hfin, W1, b1, hid);
  mlp2_kernel<<<1, 128, 0, stream>>>(hid, W2, b2, out);
}

// Round 9
// 2677.170 us; speedup vs baseline: 8.2155x; 1.4191x over previous
//
#include <hip/hip_runtime.h>
#include <hip/hip_bf16.h>
#include <cstdint>

typedef _Float16 h2 __attribute__((ext_vector_type(2)));
typedef _Float16 h4 __attribute__((ext_vector_type(4)));
typedef _Float16 h8 __attribute__((ext_vector_type(8)));
typedef float f4 __attribute__((ext_vector_type(4)));
typedef unsigned int u32x4 __attribute__((ext_vector_type(4)));
typedef unsigned long long u64;

#define S_LEN 512
#define BATCH 64
#define DM    512
#define HID   768

union h4u { u64 u; h4 v; };

static __device__ __forceinline__ h8 pack8(float4 a, float4 b) {
  h8 v;
  v[0] = (_Float16)a.x; v[1] = (_Float16)a.y;
  v[2] = (_Float16)a.z; v[3] = (_Float16)a.w;
  v[4] = (_Float16)b.x; v[5] = (_Float16)b.y;
  v[6] = (_Float16)b.z; v[7] = (_Float16)b.w;
  return v;
}

// swizzled LDS access for [row][64 k] fp16 tiles (row stride 128B)
static __device__ __forceinline__ h8 ldfrag(const _Float16* S, int row, int ke) {
  int byte = (row << 7) + (ke << 1);
  byte ^= (row & 7) << 4;
  return *(const h8*)((const char*)S + byte);
}
static __device__ __forceinline__ void stfrag(_Float16* S, int row, int ke, h8 v) {
  int byte = (row << 7) + (ke << 1);
  byte ^= (row & 7) << 4;
  *(h8*)((char*)S + byte) = v;
}

// ---------------------------------------------------------------------------
// Kernel A (MFMA): xg[dir] = gather(emb, ids) @ Wi^T + bi  (fp32 in, fp16 out)
// Tile: 128 N (Wi rows, MFMA-A) x 128 M (gathered emb rows, MFMA-B), BK=64.
// C-frag: lane holds 4 consecutive j for one (s,b) -> 8B stores in scan
// layout xg[((sl*3 + gate)*64 + b)*768 + j].
// ---------------------------------------------------------------------------
__global__ __launch_bounds__(256) void gemm1_kernel(
    const int* __restrict__ ids, const float* __restrict__ emb,
    const float* __restrict__ Wi_f, const float* __restrict__ bi_f,
    const float* __restrict__ Wi_b, const float* __restrict__ bi_b,
    int s0_f, int s0_b,
    _Float16* __restrict__ xg_f, _Float16* __restrict__ xg_b)
{
  const int mt  = blockIdx.x;      // 0..CH/2-1 (128 M rows = 2 sl x 64 b)
  const int nt  = blockIdx.y;      // 0..17     (128 N of 2304)
  const int dir = blockIdx.z;
  const float* __restrict__ Wi = dir ? Wi_b : Wi_f;
  const float* __restrict__ bi = dir ? bi_b : bi_f;
  _Float16*   __restrict__ xg  = dir ? xg_b : xg_f;
  const int s0 = dir ? s0_b : s0_f;

  __shared__ _Float16 Ws[128 * 64];   // [n][k] swizzled
  __shared__ _Float16 Es[128 * 64];   // [m][k] swizzled
  __shared__ int ids_s[128];

  const int tid = threadIdx.x;
  if (tid < 128) {
    // local m row = tid: sl = tid>>6, b = tid&63
    ids_s[tid] = ids[(tid & 63) * S_LEN + s0 + mt * 2 + (tid >> 6)];
  }

  const int w  = tid >> 6;          // wave 0..3
  const int L  = tid & 63;
  const int lh = L >> 4;            // 0..3
  const int ln = L & 15;            // 0..15
  const int wn = (w >> 1) * 64;     // wave n-base
  const int wm = (w & 1) * 64;      // wave m-base

  const int r  = tid >> 1;          // staging row 0..127
  const int kh = (tid & 1) * 32;    // staging k offset

  f4 acc[4][4];
#pragma unroll
  for (int i = 0; i < 4; ++i)
#pragma unroll
    for (int j = 0; j < 4; ++j) { acc[i][j][0]=0.f; acc[i][j][1]=0.f; acc[i][j][2]=0.f; acc[i][j][3]=0.f; }

  __syncthreads();

  for (int kt = 0; kt < DM; kt += 64) {
    {
      const float* srcW = Wi + (size_t)(nt * 128 + r) * DM + kt + kh;
      const float* srcE = emb + (size_t)ids_s[r] * DM + kt + kh;
      float4 w0 = ((const float4*)srcW)[0], w1 = ((const float4*)srcW)[1];
      float4 w2 = ((const float4*)srcW)[2], w3 = ((const float4*)srcW)[3];
      float4 w4 = ((const float4*)srcW)[4], w5 = ((const float4*)srcW)[5];
      float4 w6 = ((const float4*)srcW)[6], w7 = ((const float4*)srcW)[7];
      float4 e0 = ((const float4*)srcE)[0], e1 = ((const float4*)srcE)[1];
      float4 e2 = ((const float4*)srcE)[2], e3 = ((const float4*)srcE)[3];
      float4 e4 = ((const float4*)srcE)[4], e5 = ((const float4*)srcE)[5];
      float4 e6 = ((const float4*)srcE)[6], e7 = ((const float4*)srcE)[7];
      stfrag(Ws, r, kh + 0,  pack8(w0, w1));
      stfrag(Ws, r, kh + 8,  pack8(w2, w3));
      stfrag(Ws, r, kh + 16, pack8(w4, w5));
      stfrag(Ws, r, kh + 24, pack8(w6, w7));
      stfrag(Es, r, kh + 0,  pack8(e0, e1));
      stfrag(Es, r, kh + 8,  pack8(e2, e3));
      stfrag(Es, r, kh + 16, pack8(e4, e5));
      stfrag(Es, r, kh + 24, pack8(e6, e7));
    }
    __syncthreads();
#pragma unroll
    for (int ks = 0; ks < 2; ++ks) {
      h8 af[4], bf[4];
#pragma unroll
      for (int i = 0; i < 4; ++i) af[i] = ldfrag(Ws, wn + i * 16 + ln, ks * 32 + lh * 8);
#pragma unroll
      for (int j = 0; j < 4; ++j) bf[j] = ldfrag(Es, wm + j * 16 + ln, ks * 32 + lh * 8);
#pragma unroll
      for (int i = 0; i < 4; ++i)
#pragma unroll
        for (int j = 0; j < 4; ++j)
          acc[i][j] = __builtin_amdgcn_mfma_f32_16x16x32_f16(af[i], bf[j], acc[i][j], 0, 0, 0);
    }
    __syncthreads();
  }

  // epilogue: bias + store (lane: 4 consecutive j for one (sl,b))
#pragma unroll
  for (int i = 0; i < 4; ++i) {
    const int n_g = nt * 128 + wn + i * 16 + lh * 4;
    const int gate = n_g / 768;
    const int jj = n_g - gate * 768;
    const f4 bv = *(const f4*)&bi[n_g];
#pragma unroll
    for (int j = 0; j < 4; ++j) {
      const int m = mt * 128 + wm + j * 16 + ln;
      const int sl = m >> 6, b = m & 63;
      h4 v;
#pragma unroll
      for (int rr = 0; rr < 4; ++rr) v[rr] = (_Float16)(acc[i][j][rr] + bv[rr]);
      *(h4*)&xg[(((size_t)sl * 3 + gate) * 64 + b) * 768 + jj] = v;
    }
  }
}

// ---------------------------------------------------------------------------
// Kernel B: MFMA GRU scan. 96 blocks x 256 threads, weights in VGPR/AGPR.
// Protocol (placement-independent, no barriers, no release/acquire):
//  - payload: hx[dir][parity][b][g]  (16B granule = 8 fp16, k-major groups)
//  - tags:    tags[dir][b][16] u32, monotonically = last stored step+1
//  - producer: store payload (sc0 sc1), vmcnt(0), __syncthreads,
//              lanes 0..15 store tag (sc0 sc1)
//  - consumer: spin on 12 tags >= sg, then load payload (proven complete),
//              stage to XOR-swizzled LDS [g][b^g&7], MFMA.
// ---------------------------------------------------------------------------
__global__ __launch_bounds__(256, 1) void scan_mfma_kernel(
    const float* __restrict__ Wh_f, const float* __restrict__ bh_f,
    const float* __restrict__ Wh_b, const float* __restrict__ bh_b,
    const _Float16* __restrict__ xg_f, const _Float16* __restrict__ xg_b,
    char* __restrict__ hx,          // payload: 2*2*64*96*16 bytes
    unsigned* __restrict__ tags,    // 2*64*16 u32
    float* __restrict__ hfin,       // [dir][64][768] fp32 chunk-save
    int step0, int nsteps)
{
  const int blk = blockIdx.x;       // 0..95
  const int dir = blk / 48;
  const int l   = blk - dir * 48;   // 0..47
  const int bg  = l / 12;           // batch group 0..3
  const int jb  = l - bg * 12;      // unit twelfth 0..11

  const float* __restrict__ Wh = dir ? Wh_b : Wh_f;
  const float* __restrict__ bh = dir ? bh_b : bh_f;
  const _Float16* __restrict__ xg = dir ? xg_b : xg_f;
  char*     payB = hx + (size_t)dir * 2 * 64 * 96 * 16;
  unsigned* tagB = tags + dir * 64 * 16;
  float*    hfd  = hfin + (size_t)dir * 64 * 768;

  const int tid = threadIdx.x;
  const int w   = tid >> 6;         // wave 0..3
  const int L   = tid & 63;
  const int lh  = L >> 4;           // 0..3
  const int ln  = L & 15;           // 0..15
  const int jt  = jb * 4 + w;       // unit tile 0..47
  const int jrow = jt * 16 + ln;    // A-fragment row (j)
  const int j0l  = jt * 16 + lh * 4;  // 4 owned units
  const int bglob = bg * 16 + ln;   // owned batch column (producer)
  const int bb  = tid >> 4;         // consumer batch row 0..15
  const int qi  = tid & 15;         // consumer granule base

  __shared__ __align__(16) unsigned char hs[96 * 256];  // [g][16 b][16B] 24KB

  // ---- Wh as A-fragments: A[gate][ks] elem e -> Wh[jrow][ks*32+lh*8+e]
  h8 A[3][24];
#pragma unroll
  for (int g = 0; g < 3; ++g)
#pragma unroll
    for (int ks = 0; ks < 24; ++ks) {
      const float* src = Wh + (size_t)(g * 768 + jrow) * 768 + ks * 32 + lh * 8;
      float4 w0 = ((const float4*)src)[0];
      float4 w1 = ((const float4*)src)[1];
      A[g][ks] = pack8(w0, w1);
    }

  f4 bhv[3];
#pragma unroll
  for (int g = 0; g < 3; ++g) bhv[g] = *(const f4*)&bh[g * 768 + j0l];

  // ---- fp32 h master
  f4 hm;
  if (step0 == 0) { hm[0]=0.f; hm[1]=0.f; hm[2]=0.f; hm[3]=0.f; }
  else {
    const float* src = &hfd[(size_t)bglob * 768 + j0l];
    asm volatile("global_load_dwordx4 %0, %1, off sc0 sc1\n\t"
                 "s_waitcnt vmcnt(0)"
                 : "=&v"(hm) : "v"(src) : "memory");
  }

  unsigned* mytag = tagB + (bg * 16 + bb) * 16;          // consumer's 12 tags
  const char* pcb = payB;                                 // payload base
  // producer payload slot: granule jt*2+(lh>>1), half lh&1
  const size_t pslot = ((size_t)bglob * 96 + jt * 2 + (lh >> 1)) * 16
                     + (size_t)(lh & 1) * 8;
  const int swb = (bb ^ (qi & 7)) * 16;   // swizzled LDS column for stager

  for (int t = 0; t < nsteps; ++t) {
    const int sg = step0 + t;
    const int pin = sg & 1, pout = pin ^ 1;

    // xg loads for this step (plain cached; overlap the spin)
    const int lsl = dir ? (nsteps - 1 - t) : t;
    const _Float16* xrow = xg + (((size_t)lsl * 3) * 64 + bglob) * 768 + j0l;
    h4 xr4 = *(const h4*)xrow;
    h4 xz4 = *(const h4*)(xrow + (size_t)64 * 768);
    h4 xn4 = *(const h4*)(xrow + (size_t)2 * 64 * 768);

    // ---- tag spin: all 12 producer tags for batch (bg*16+bb) >= sg
    {
      u32x4 t0, t1, t2;
      for (;;) {
        asm volatile(
          "global_load_dwordx4 %0, %3, off sc0 sc1\n\t"
          "global_load_dwordx4 %1, %4, off sc0 sc1\n\t"
          "global_load_dwordx4 %2, %5, off sc0 sc1\n\t"
          "s_waitcnt vmcnt(0)"
          : "=&v"(t0), "=&v"(t1), "=&v"(t2)
          : "v"(mytag), "v"(mytag + 4), "v"(mytag + 8)
          : "memory");
        unsigned m01 = min(min(t0[0], t0[1]), min(t0[2], t0[3]));
        unsigned m23 = min(min(t1[0], t1[1]), min(t1[2], t1[3]));
        unsigned m45 = min(min(t2[0], t2[1]), min(t2[2], t2[3]));
        if (min(min(m01, m23), m45) >= (unsigned)sg) break;
      }
    }

    // ---- payload: 6 granules of 16B for batch bb (proven complete)
    u32x4 p0, p1, p2, p3, p4, p5;
    {
      const char* pc = pcb + (((size_t)pin * 64 + bg * 16 + bb) * 96 + qi) * 16;
      asm volatile(
        "global_load_dwordx4 %0, %6, off sc0 sc1\n\t"
        "global_load_dwordx4 %1, %7, off sc0 sc1\n\t"
        "global_load_dwordx4 %2, %8, off sc0 sc1\n\t"
        "global_load_dwordx4 %3, %9, off sc0 sc1\n\t"
        "global_load_dwordx4 %4, %10, off sc0 sc1\n\t"
        "global_load_dwordx4 %5, %11, off sc0 sc1\n\t"
        "s_waitcnt vmcnt(0)"
        : "=&v"(p0), "=&v"(p1), "=&v"(p2), "=&v"(p3), "=&v"(p4), "=&v"(p5)
        : "v"(pc), "v"(pc + 16*16), "v"(pc + 32*16), "v"(pc + 48*16),
          "v"(pc + 64*16), "v"(pc + 80*16)
        : "memory");
    }

    // ---- stage to LDS [g][b^ (g&7)] (XOR-swizzled: 16-way -> 2-way free)
    *(u32x4*)(hs + (qi +  0) * 256 + swb) = p0;
    *(u32x4*)(hs + (qi + 16) * 256 + swb) = p1;
    *(u32x4*)(hs + (qi + 32) * 256 + swb) = p2;
    *(u32x4*)(hs + (qi + 48) * 256 + swb) = p3;
    *(u32x4*)(hs + (qi + 64) * 256 + swb) = p4;
    *(u32x4*)(hs + (qi + 80) * 256 + swb) = p5;
    __syncthreads();

    // ---- B-fragments from LDS + MFMA
    f4 Cr, Cz, Cn;
    Cr[0]=0.f;Cr[1]=0.f;Cr[2]=0.f;Cr[3]=0.f;
    Cz = Cr; Cn = Cr;
#pragma unroll
    for (int ks = 0; ks < 24; ++ks) {
      const int g = ks * 4 + lh;
      h8 Bf = *(const h8*)(hs + g * 256 + ((ln ^ (g & 7)) * 16));
      Cr = __builtin_amdgcn_mfma_f32_16x16x32_f16(A[0][ks], Bf, Cr, 0, 0, 0);
      Cz = __builtin_amdgcn_mfma_f32_16x16x32_f16(A[1][ks], Bf, Cz, 0, 0, 0);
      Cn = __builtin_amdgcn_mfma_f32_16x16x32_f16(A[2][ks], Bf, Cn, 0, 0, 0);
    }

    // ---- gates
    f4 hnew;
    h4u st;
#pragma unroll
    for (int r = 0; r < 4; ++r) {
      float rr = 1.f / (1.f + __expf(-((float)xr4[r] + Cr[r] + bhv[0][r])));
      float zz = 1.f / (1.f + __expf(-((float)xz4[r] + Cz[r] + bhv[1][r])));
      float nn = tanhf((float)xn4[r] + rr * (Cn[r] + bhv[2][r]));
      hnew[r] = (1.f - zz) * nn + zz * hm[r];
      st.v[r] = (_Float16)hnew[r];
    }
    hm = hnew;

    // ---- producer: payload store, drain, block-sync, tag store
    {
      char* dst = payB + (size_t)pout * 64 * 96 * 16 + pslot;
      asm volatile("global_store_dwordx2 %0, %1, off sc0 sc1"
                   :: "v"(dst), "v"(st.u) : "memory");
      asm volatile("s_waitcnt vmcnt(0)" ::: "memory");
    }
    __syncthreads();
    if (tid < 16) {
      unsigned tv = (unsigned)(sg + 1);
      unsigned* ta = tagB + (bg * 16 + tid) * 16 + jb;
      asm volatile("global_store_dword %0, %1, off sc0 sc1"
                   :: "v"(ta), "v"(tv) : "memory");
    }
  }

  // chunk-save fp32 h (read by next launch's same lane, sc0 sc1 both sides)
  {
    float* dst = &hfd[(size_t)bglob * 768 + j0l];
    asm volatile("global_store_dwordx4 %0, %1, off sc0 sc1"
                 :: "v"(dst), "v"(hm) : "memory");
  }
}

// ---------------------------------------------------------------------------
// MLP head.  hfin layout: [dir][b][j] fp32.
// ---------------------------------------------------------------------------
__global__ __launch_bounds__(256) void mlp1_kernel(
    const float* __restrict__ hfin, const float* __restrict__ W1,
    const float* __restrict__ b1, float* __restrict__ hid)
{
  const int c = blockIdx.x * 4 + (threadIdx.x >> 6);
  const int b = threadIdx.x & 63;
  const float* __restrict__ hf = hfin + (size_t)b * 768;
  const float* __restrict__ hb = hfin + (size_t)(64 + b) * 768;
  const float* __restrict__ w = W1 + (size_t)c * 1536;
  float acc = b1[c];
  for (int k = 0; k < 768; k += 4) {
    float4 hv = *(const float4*)&hf[k];
    float4 wv = *(const float4*)&w[k];
    acc += hv.x * wv.x + hv.y * wv.y + hv.z * wv.z + hv.w * wv.w;
  }
  for (int k = 0; k < 768; k += 4) {
    float4 hv = *(const float4*)&hb[k];
    float4 wv = *(const float4*)&w[768 + k];
    acc += hv.x * wv.x + hv.y * wv.y + hv.z * wv.z + hv.w * wv.w;
  }
  hid[(size_t)c * 64 + b] = fmaxf(acc, 0.f);
}

__global__ void mlp2_kernel(const float* __restrict__ hid,
                            const float* __restrict__ W2,
                            const float* __restrict__ b2,
                            float* __restrict__ out)
{
  const int tid = threadIdx.x;      // 128 threads
  const int b = tid & 63, cls = tid >> 6;
  const float* __restrict__ w = W2 + cls * 768;
  float acc = b2[cls];
  for (int k = 0; k < 768; ++k) acc += hid[(size_t)k * 64 + b] * w[k];
  out[b * 2 + cls] = acc;
}

// ---------------------------------------------------------------------------
extern "C" void kernel_launch(void* const* d_in, const int* in_sizes, int n_in,
                              void* d_out, int out_size, void* d_ws, size_t ws_size,
                              hipStream_t stream)
{
  const int*   ids  = (const int*)d_in[0];
  const float* emb  = (const float*)d_in[1];
  const float* Wi_f = (const float*)d_in[2];
  const float* Wh_f = (const float*)d_in[3];
  const float* bi_f = (const float*)d_in[4];
  const float* bh_f = (const float*)d_in[5];
  const float* Wi_b = (const float*)d_in[6];
  const float* Wh_b = (const float*)d_in[7];
  const float* bi_b = (const float*)d_in[8];
  const float* bh_b = (const float*)d_in[9];
  const float* W1   = (const float*)d_in[10];
  const float* b1   = (const float*)d_in[11];
  const float* W2   = (const float*)d_in[12];
  const float* b2   = (const float*)d_in[13];
  float* out = (float*)d_out;

  // state sizes (bytes)
  const size_t B_HX   = (size_t)2 * 2 * 64 * 96 * 16;   // 393216
  const size_t B_TAG  = (size_t)2 * 64 * 16 * 4;        // 8192
  const size_t B_HFIN = (size_t)2 * 64 * 768 * 4;       // 393216
  const size_t B_HID  = (size_t)HID * BATCH * 4;        // 196608
  const size_t state_bytes = B_HX + B_TAG + B_HFIN + B_HID;

  // choose chunk size: largest CH with 2*CH*64*2304 fp16 xg + state <= ws
  int CH = 512;
  while (CH > 8) {
    size_t need = (size_t)4 * CH * 64 * 2304 + state_bytes;
    if (need <= ws_size) break;
    CH >>= 1;
  }
  const size_t SZ_XG = (size_t)CH * 64 * 2304;          // halves per direction

  char* ws = (char*)d_ws;
  _Float16* xg_f = (_Float16*)ws;
  _Float16* xg_b = xg_f + SZ_XG;
  char*     hx   = (char*)(xg_b + SZ_XG);
  unsigned* tags = (unsigned*)(hx + B_HX);
  float*    hfin = (float*)((char*)tags + B_TAG);
  float*    hid  = (float*)((char*)hfin + B_HFIN);

  // zero hx + tags + hfin + hid (contiguous) every call
  (void)hipMemsetAsync(hx, 0, state_bytes, stream);

  const int nch = 512 / CH;
  for (int c = 0; c < nch; ++c) {
    const int s0f = c * CH;                 // fwd window start
    const int s0b = 512 - (c + 1) * CH;     // bwd window start
    gemm1_kernel<<<dim3(CH / 2, 18, 2), 256, 0, stream>>>(
        ids, emb, Wi_f, bi_f, Wi_b, bi_b, s0f, s0b, xg_f, xg_b);
    scan_mfma_kernel<<<96, 256, 0, stream>>>(
        Wh_f, bh_f, Wh_b, bh_b, xg_f, xg_b, hx, tags, hfin, c * CH, CH);
  }
  mlp1_kernel<<<192, 256, 0, stream>>>(hfin, W1, b1, hid);
  mlp2_kernel<<<1, 128, 0, stream>>>(hid, W2, b2, out);
}

// Round 11
// 2593.201 us; speedup vs baseline: 8.4816x; 1.0324x over previous
//
#include <hip/hip_runtime.h>
#include <hip/hip_bf16.h>
#include <cstdint>

typedef _Float16 h2 __attribute__((ext_vector_type(2)));
typedef _Float16 h4 __attribute__((ext_vector_type(4)));
typedef _Float16 h8 __attribute__((ext_vector_type(8)));
typedef float f4 __attribute__((ext_vector_type(4)));
typedef unsigned long long u64;
typedef unsigned int u32;

#define S_LEN 512
#define BATCH 64
#define DM    512
#define HID   768

union h4u { u64 u; h4 v; };

static __device__ __forceinline__ h8 pack8(float4 a, float4 b) {
  h8 v;
  v[0] = (_Float16)a.x; v[1] = (_Float16)a.y;
  v[2] = (_Float16)a.z; v[3] = (_Float16)a.w;
  v[4] = (_Float16)b.x; v[5] = (_Float16)b.y;
  v[6] = (_Float16)b.z; v[7] = (_Float16)b.w;
  return v;
}

// swizzled LDS access for [row][64 k] fp16 tiles (row stride 128B)
static __device__ __forceinline__ h8 ldfrag(const _Float16* S, int row, int ke) {
  int byte = (row << 7) + (ke << 1);
  byte ^= (row & 7) << 4;
  return *(const h8*)((const char*)S + byte);
}
static __device__ __forceinline__ void stfrag(_Float16* S, int row, int ke, h8 v) {
  int byte = (row << 7) + (ke << 1);
  byte ^= (row & 7) << 4;
  *(h8*)((char*)S + byte) = v;
}

// ---------------------------------------------------------------------------
// Kernel A (MFMA): xg[dir] = gather(emb, ids) @ Wi^T + bi  (fp32 in, fp16 out)
// ---------------------------------------------------------------------------
__global__ __launch_bounds__(256) void gemm1_kernel(
    const int* __restrict__ ids, const float* __restrict__ emb,
    const float* __restrict__ Wi_f, const float* __restrict__ bi_f,
    const float* __restrict__ Wi_b, const float* __restrict__ bi_b,
    int s0_f, int s0_b,
    _Float16* __restrict__ xg_f, _Float16* __restrict__ xg_b)
{
  const int mt  = blockIdx.x;      // 0..CH/2-1 (128 M rows = 2 sl x 64 b)
  const int nt  = blockIdx.y;      // 0..17     (128 N of 2304)
  const int dir = blockIdx.z;
  const float* __restrict__ Wi = dir ? Wi_b : Wi_f;
  const float* __restrict__ bi = dir ? bi_b : bi_f;
  _Float16*   __restrict__ xg  = dir ? xg_b : xg_f;
  const int s0 = dir ? s0_b : s0_f;

  __shared__ _Float16 Ws[128 * 64];   // [n][k] swizzled
  __shared__ _Float16 Es[128 * 64];   // [m][k] swizzled
  __shared__ int ids_s[128];

  const int tid = threadIdx.x;
  if (tid < 128) {
    ids_s[tid] = ids[(tid & 63) * S_LEN + s0 + mt * 2 + (tid >> 6)];
  }

  const int w  = tid >> 6;          // wave 0..3
  const int L  = tid & 63;
  const int lh = L >> 4;            // 0..3
  const int ln = L & 15;            // 0..15
  const int wn = (w >> 1) * 64;     // wave n-base
  const int wm = (w & 1) * 64;      // wave m-base

  const int r  = tid >> 1;          // staging row 0..127
  const int kh = (tid & 1) * 32;    // staging k offset

  f4 acc[4][4];
#pragma unroll
  for (int i = 0; i < 4; ++i)
#pragma unroll
    for (int j = 0; j < 4; ++j) { acc[i][j][0]=0.f; acc[i][j][1]=0.f; acc[i][j][2]=0.f; acc[i][j][3]=0.f; }

  __syncthreads();

  for (int kt = 0; kt < DM; kt += 64) {
    {
      const float* srcW = Wi + (size_t)(nt * 128 + r) * DM + kt + kh;
      const float* srcE = emb + (size_t)ids_s[r] * DM + kt + kh;
      float4 w0 = ((const float4*)srcW)[0], w1 = ((const float4*)srcW)[1];
      float4 w2 = ((const float4*)srcW)[2], w3 = ((const float4*)srcW)[3];
      float4 w4 = ((const float4*)srcW)[4], w5 = ((const float4*)srcW)[5];
      float4 w6 = ((const float4*)srcW)[6], w7 = ((const float4*)srcW)[7];
      float4 e0 = ((const float4*)srcE)[0], e1 = ((const float4*)srcE)[1];
      float4 e2 = ((const float4*)srcE)[2], e3 = ((const float4*)srcE)[3];
      float4 e4 = ((const float4*)srcE)[4], e5 = ((const float4*)srcE)[5];
      float4 e6 = ((const float4*)srcE)[6], e7 = ((const float4*)srcE)[7];
      stfrag(Ws, r, kh + 0,  pack8(w0, w1));
      stfrag(Ws, r, kh + 8,  pack8(w2, w3));
      stfrag(Ws, r, kh + 16, pack8(w4, w5));
      stfrag(Ws, r, kh + 24, pack8(w6, w7));
      stfrag(Es, r, kh + 0,  pack8(e0, e1));
      stfrag(Es, r, kh + 8,  pack8(e2, e3));
      stfrag(Es, r, kh + 16, pack8(e4, e5));
      stfrag(Es, r, kh + 24, pack8(e6, e7));
    }
    __syncthreads();
#pragma unroll
    for (int ks = 0; ks < 2; ++ks) {
      h8 af[4], bf[4];
#pragma unroll
      for (int i = 0; i < 4; ++i) af[i] = ldfrag(Ws, wn + i * 16 + ln, ks * 32 + lh * 8);
#pragma unroll
      for (int j = 0; j < 4; ++j) bf[j] = ldfrag(Es, wm + j * 16 + ln, ks * 32 + lh * 8);
#pragma unroll
      for (int i = 0; i < 4; ++i)
#pragma unroll
        for (int j = 0; j < 4; ++j)
          acc[i][j] = __builtin_amdgcn_mfma_f32_16x16x32_f16(af[i], bf[j], acc[i][j], 0, 0, 0);
    }
    __syncthreads();
  }

#pragma unroll
  for (int i = 0; i < 4; ++i) {
    const int n_g = nt * 128 + wn + i * 16 + lh * 4;
    const int gate = n_g / 768;
    const int jj = n_g - gate * 768;
    const f4 bv = *(const f4*)&bi[n_g];
#pragma unroll
    for (int j = 0; j < 4; ++j) {
      const int m = mt * 128 + wm + j * 16 + ln;
      const int sl = m >> 6, b = m & 63;
      h4 v;
#pragma unroll
      for (int rr = 0; rr < 4; ++rr) v[rr] = (_Float16)(acc[i][j][rr] + bv[rr]);
      *(h4*)&xg[(((size_t)sl * 3 + gate) * 64 + b) * 768 + jj] = v;
    }
  }
}

// ---------------------------------------------------------------------------
// Kernel B: MFMA GRU scan with value-embedded tags (ONE LLC trip per step).
// h granule = 8B = 4 fp16 in [-1,1] (bit14 free) + 4-bit step tag in bit14s.
// Producer: clamp, pack tag (sg+1)&15, one dwordx2 sc0sc1 store, no ack wait.
// Consumer: poll its batch row (6 pairs x 2 dwordx2, stride 256B) until all
// tags == sg&15; payload IS the data. Skew<=1 => staleness<=2 => no alias.
// ---------------------------------------------------------------------------
__global__ __launch_bounds__(256, 1) void scan_mfma_kernel(
    const float* __restrict__ Wh_f, const float* __restrict__ bh_f,
    const float* __restrict__ Wh_b, const float* __restrict__ bh_b,
    const _Float16* __restrict__ xg_f, const _Float16* __restrict__ xg_b,
    char* __restrict__ hx,          // payload: 2 dir * 2 par * 64 b * 1536B
    float* __restrict__ hfin,       // [dir][64][768] fp32 chunk-save
    int step0, int nsteps)
{
  const int blk = blockIdx.x;       // 0..95
  const int dir = blk / 48;
  const int l   = blk - dir * 48;   // 0..47
  const int bg  = l / 12;           // batch group 0..3
  const int jb  = l - bg * 12;      // unit twelfth 0..11

  const float* __restrict__ Wh = dir ? Wh_b : Wh_f;
  const float* __restrict__ bh = dir ? bh_b : bh_f;
  const _Float16* __restrict__ xg = dir ? xg_b : xg_f;
  char*  payB = hx + (size_t)dir * 2 * 64 * 1536;
  float* hfd  = hfin + (size_t)dir * 64 * 768;

  const int tid = threadIdx.x;
  const int w   = tid >> 6;         // wave 0..3
  const int L   = tid & 63;
  const int lh  = L >> 4;           // 0..3
  const int ln  = L & 15;           // 0..15
  const int jt  = jb * 4 + w;       // unit tile 0..47
  const int jrow = jt * 16 + ln;    // A-fragment row (j)
  const int j0l  = jt * 16 + lh * 4;  // 4 owned units
  const int bglob = bg * 16 + ln;   // owned batch column (producer)
  const int bb  = tid >> 4;         // consumer batch row 0..15
  const int qi  = tid & 15;         // consumer pair-group base

  __shared__ __align__(16) unsigned char hs[96 * 256];  // [pair][16 b][16B]

  // ---- Wh as A-fragments
  h8 A[3][24];
#pragma unroll
  for (int g = 0; g < 3; ++g)
#pragma unroll
    for (int ks = 0; ks < 24; ++ks) {
      const float* src = Wh + (size_t)(g * 768 + jrow) * 768 + ks * 32 + lh * 8;
      float4 w0 = ((const float4*)src)[0];
      float4 w1 = ((const float4*)src)[1];
      A[g][ks] = pack8(w0, w1);
    }

  f4 bhv[3];
#pragma unroll
  for (int g = 0; g < 3; ++g) bhv[g] = *(const f4*)&bh[g * 768 + j0l];

  // ---- fp32 h master
  f4 hm;
  if (step0 == 0) { hm[0]=0.f; hm[1]=0.f; hm[2]=0.f; hm[3]=0.f; }
  else {
    const float* src = &hfd[(size_t)bglob * 768 + j0l];
    asm volatile("global_load_dwordx4 %0, %1, off sc0 sc1\n\t"
                 "s_waitcnt vmcnt(0)"
                 : "=&v"(hm) : "v"(src) : "memory");
  }

  // producer slot: batch bglob, granule jt*4+lh (4 units), 8B
  char* const pslot = payB + (size_t)bglob * 1536 + (size_t)(jt * 4 + lh) * 8;
  // consumer: batch bb, pair p = qi+16*i at byte qi*16 + 256*i
  const char* const crow = payB + (size_t)(bg * 16 + bb) * 1536 + qi * 16;
  const int swb = (bb ^ (qi & 7)) * 16;   // swizzled LDS column (row&7==qi&7)

  for (int t = 0; t < nsteps; ++t) {
    const int sg = step0 + t;
    const int pin = sg & 1, pout = pin ^ 1;

    // xg loads for this step (overlap the poll's vmcnt)
    const int lsl = dir ? (nsteps - 1 - t) : t;
    const _Float16* xrow = xg + (((size_t)lsl * 3) * 64 + bglob) * 768 + j0l;
    h4 xr4 = *(const h4*)xrow;
    h4 xz4 = *(const h4*)(xrow + (size_t)64 * 768);
    h4 xn4 = *(const h4*)(xrow + (size_t)2 * 64 * 768);

    // ---- poll payload until all 12 embedded tags == sg&15
    const u32 texp = (u32)sg & 15u;
    const u32 e0 = ((texp & 1u) << 14) | ((texp & 2u) << 29);
    const u32 e1 = ((texp & 4u) << 12) | ((texp & 8u) << 27);
    const char* pc = crow + (size_t)pin * 64 * 1536;
    u64 q0,q1,q2,q3,q4,q5,q6,q7,q8,q9,q10,q11;
    for (;;) {
      asm volatile(
        "global_load_dwordx2 %0, %12, off sc0 sc1\n\t"
        "global_load_dwordx2 %1, %12, off offset:8 sc0 sc1\n\t"
        "global_load_dwordx2 %2, %13, off sc0 sc1\n\t"
        "global_load_dwordx2 %3, %13, off offset:8 sc0 sc1\n\t"
        "global_load_dwordx2 %4, %14, off sc0 sc1\n\t"
        "global_load_dwordx2 %5, %14, off offset:8 sc0 sc1\n\t"
        "global_load_dwordx2 %6, %15, off sc0 sc1\n\t"
        "global_load_dwordx2 %7, %15, off offset:8 sc0 sc1\n\t"
        "global_load_dwordx2 %8, %16, off sc0 sc1\n\t"
        "global_load_dwordx2 %9, %16, off offset:8 sc0 sc1\n\t"
        "global_load_dwordx2 %10, %17, off sc0 sc1\n\t"
        "global_load_dwordx2 %11, %17, off offset:8 sc0 sc1\n\t"
        "s_waitcnt vmcnt(0)"
        : "=&v"(q0), "=&v"(q1), "=&v"(q2), "=&v"(q3), "=&v"(q4), "=&v"(q5),
          "=&v"(q6), "=&v"(q7), "=&v"(q8), "=&v"(q9), "=&v"(q10), "=&v"(q11)
        : "v"(pc), "v"(pc + 256), "v"(pc + 512),
          "v"(pc + 768), "v"(pc + 1024), "v"(pc + 1280)
        : "memory");
      u32 bad = 0;
      u64 qs[12] = {q0,q1,q2,q3,q4,q5,q6,q7,q8,q9,q10,q11};
#pragma unroll
      for (int i = 0; i < 12; ++i) {
        u32 lo = (u32)qs[i], hi = (u32)(qs[i] >> 32);
        bad |= ((lo & 0x40004000u) ^ e0) | ((hi & 0x40004000u) ^ e1);
      }
      if (bad == 0) break;
    }
    // clear tag bits and stage to LDS (pair rows qi+16i, swizzled col)
    {
      const u64 CM = 0xBFFFBFFFBFFFBFFFull;
      u64 qa[12] = {q0&CM,q1&CM,q2&CM,q3&CM,q4&CM,q5&CM,q6&CM,q7&CM,q8&CM,q9&CM,q10&CM,q11&CM};
#pragma unroll
      for (int i = 0; i < 6; ++i) {
        u64* d = (u64*)(hs + (qi + 16 * i) * 256 + swb);
        d[0] = qa[2 * i];
        d[1] = qa[2 * i + 1];
      }
    }
    __syncthreads();

    // ---- B-fragments from LDS + MFMA  (pair row p = ks*4+lh)
    f4 Cr, Cz, Cn;
    Cr[0]=0.f;Cr[1]=0.f;Cr[2]=0.f;Cr[3]=0.f;
    Cz = Cr; Cn = Cr;
#pragma unroll
    for (int ks = 0; ks < 24; ++ks) {
      const int p = ks * 4 + lh;
      h8 Bf = *(const h8*)(hs + p * 256 + ((ln ^ (p & 7)) * 16));
      Cr = __builtin_amdgcn_mfma_f32_16x16x32_f16(A[0][ks], Bf, Cr, 0, 0, 0);
      Cz = __builtin_amdgcn_mfma_f32_16x16x32_f16(A[1][ks], Bf, Cz, 0, 0, 0);
      Cn = __builtin_amdgcn_mfma_f32_16x16x32_f16(A[2][ks], Bf, Cn, 0, 0, 0);
    }

    // ---- gates
    f4 hnew;
    h4u st;
#pragma unroll
    for (int r = 0; r < 4; ++r) {
      float rr = 1.f / (1.f + __expf(-((float)xr4[r] + Cr[r] + bhv[0][r])));
      float zz = 1.f / (1.f + __expf(-((float)xz4[r] + Cz[r] + bhv[1][r])));
      float nn = tanhf((float)xn4[r] + rr * (Cn[r] + bhv[2][r]));
      hnew[r] = (1.f - zz) * nn + zz * hm[r];
      st.v[r] = (_Float16)fminf(1.f, fmaxf(-1.f, hnew[r]));
    }
    hm = hnew;

    // ---- producer: embed tag (sg+1)&15 in bit14s, single 8B store
    {
      const u32 tw = (u32)(sg + 1) & 15u;
      u32 lo = (u32)st.u, hi = (u32)(st.u >> 32);
      lo |= ((tw & 1u) << 14) | ((tw & 2u) << 29);
      hi |= ((tw & 4u) << 12) | ((tw & 8u) << 27);
      u64 pv = ((u64)hi << 32) | lo;
      char* dst = pslot + (size_t)pout * 64 * 1536;
      asm volatile("global_store_dwordx2 %0, %1, off sc0 sc1"
                   :: "v"(dst), "v"(pv) : "memory");
    }
    __syncthreads();   // protect hs reuse next iteration
  }

  // chunk-save fp32 h
  {
    float* dst = &hfd[(size_t)bglob * 768 + j0l];
    asm volatile("global_store_dwordx4 %0, %1, off sc0 sc1"
                 :: "v"(dst), "v"(hm) : "memory");
  }
}

// ---------------------------------------------------------------------------
// MLP head.  hfin layout: [dir][b][j] fp32.
// ---------------------------------------------------------------------------
__global__ __launch_bounds__(256) void mlp1_kernel(
    const float* __restrict__ hfin, const float* __restrict__ W1,
    const float* __restrict__ b1, float* __restrict__ hid)
{
  const int c = blockIdx.x * 4 + (threadIdx.x >> 6);
  const int b = threadIdx.x & 63;
  const float* __restrict__ hf = hfin + (size_t)b * 768;
  const float* __restrict__ hb = hfin + (size_t)(64 + b) * 768;
  const float* __restrict__ w = W1 + (size_t)c * 1536;
  float acc = b1[c];
  for (int k = 0; k < 768; k += 4) {
    float4 hv = *(const float4*)&hf[k];
    float4 wv = *(const float4*)&w[k];
    acc += hv.x * wv.x + hv.y * wv.y + hv.z * wv.z + hv.w * wv.w;
  }
  for (int k = 0; k < 768; k += 4) {
    float4 hv = *(const float4*)&hb[k];
    float4 wv = *(const float4*)&w[768 + k];
    acc += hv.x * wv.x + hv.y * wv.y + hv.z * wv.z + hv.w * wv.w;
  }
  hid[(size_t)c * 64 + b] = fmaxf(acc, 0.f);
}

__global__ void mlp2_kernel(const float* __restrict__ hid,
                            const float* __restrict__ W2,
                            const float* __restrict__ b2,
                            float* __restrict__ out)
{
  const int tid = threadIdx.x;      // 128 threads
  const int b = tid & 63, cls = tid >> 6;
  const float* __restrict__ w = W2 + cls * 768;
  float acc = b2[cls];
  for (int k = 0; k < 768; ++k) acc += hid[(size_t)k * 64 + b] * w[k];
  out[b * 2 + cls] = acc;
}

// ---------------------------------------------------------------------------
extern "C" void kernel_launch(void* const* d_in, const int* in_sizes, int n_in,
                              void* d_out, int out_size, void* d_ws, size_t ws_size,
                              hipStream_t stream)
{
  const int*   ids  = (const int*)d_in[0];
  const float* emb  = (const float*)d_in[1];
  const float* Wi_f = (const float*)d_in[2];
  const float* Wh_f = (const float*)d_in[3];
  const float* bi_f = (const float*)d_in[4];
  const float* bh_f = (const float*)d_in[5];
  const float* Wi_b = (const float*)d_in[6];
  const float* Wh_b = (const float*)d_in[7];
  const float* bi_b = (const float*)d_in[8];
  const float* bh_b = (const float*)d_in[9];
  const float* W1   = (const float*)d_in[10];
  const float* b1   = (const float*)d_in[11];
  const float* W2   = (const float*)d_in[12];
  const float* b2   = (const float*)d_in[13];
  float* out = (float*)d_out;

  // state sizes (bytes)
  const size_t B_HX   = (size_t)2 * 2 * 64 * 1536;      // 393216
  const size_t B_HFIN = (size_t)2 * 64 * 768 * 4;       // 393216
  const size_t B_HID  = (size_t)HID * BATCH * 4;        // 196608
  const size_t state_bytes = B_HX + B_HFIN + B_HID;

  // choose chunk size: largest CH with 2*CH*64*2304 fp16 xg + state <= ws
  int CH = 512;
  while (CH > 8) {
    size_t need = (size_t)4 * CH * 64 * 2304 + state_bytes;
    if (need <= ws_size) break;
    CH >>= 1;
  }
  const size_t SZ_XG = (size_t)CH * 64 * 2304;          // halves per direction

  char* ws = (char*)d_ws;
  _Float16* xg_f = (_Float16*)ws;
  _Float16* xg_b = xg_f + SZ_XG;
  char*     hx   = (char*)(xg_b + SZ_XG);
  float*    hfin = (float*)(hx + B_HX);
  float*    hid  = (float*)((char*)hfin + B_HFIN);

  // zero hx + hfin + hid (contiguous) every call
  (void)hipMemsetAsync(hx, 0, state_bytes, stream);

  const int nch = 512 / CH;
  for (int c = 0; c < nch; ++c) {
    const int s0f = c * CH;                 // fwd window start
    const int s0b = 512 - (c + 1) * CH;     // bwd window start
    gemm1_kernel<<<dim3(CH / 2, 18, 2), 256, 0, stream>>>(
        ids, emb, Wi_f, bi_f, Wi_b, bi_b, s0f, s0b, xg_f, xg_b);
    scan_mfma_kernel<<<96, 256, 0, stream>>>(
        Wh_f, bh_f, Wh_b, bh_b, xg_f, xg_b, hx, hfin, c * CH, CH);
  }
  mlp1_kernel<<<192, 256, 0, stream>>>(hfin, W1, b1, hid);
  mlp2_kernel<<<1, 128, 0, stream>>>(hid, W2, b2, out);
}

// Round 12
// 2366.399 us; speedup vs baseline: 9.2945x; 1.0958x over previous
//
#include <hip/hip_runtime.h>
#include <hip/hip_bf16.h>
#include <cstdint>

typedef _Float16 h2 __attribute__((ext_vector_type(2)));
typedef _Float16 h4 __attribute__((ext_vector_type(4)));
typedef _Float16 h8 __attribute__((ext_vector_type(8)));
typedef float f4 __attribute__((ext_vector_type(4)));
typedef unsigned long long u64;
typedef unsigned int u32;

#define S_LEN 512
#define BATCH 64
#define DM    512
#define HID   768

union h4u { u64 u; h4 v; };

static __device__ __forceinline__ h8 pack8(float4 a, float4 b) {
  h8 v;
  v[0] = (_Float16)a.x; v[1] = (_Float16)a.y;
  v[2] = (_Float16)a.z; v[3] = (_Float16)a.w;
  v[4] = (_Float16)b.x; v[5] = (_Float16)b.y;
  v[6] = (_Float16)b.z; v[7] = (_Float16)b.w;
  return v;
}

// swizzled LDS access for [row][64 k] fp16 tiles (row stride 128B)
static __device__ __forceinline__ h8 ldfrag(const _Float16* S, int row, int ke) {
  int byte = (row << 7) + (ke << 1);
  byte ^= (row & 7) << 4;
  return *(const h8*)((const char*)S + byte);
}
static __device__ __forceinline__ void stfrag(_Float16* S, int row, int ke, h8 v) {
  int byte = (row << 7) + (ke << 1);
  byte ^= (row & 7) << 4;
  *(h8*)((char*)S + byte) = v;
}

// ---------------------------------------------------------------------------
// gemm body (device): xg[dir] = gather(emb, ids) @ Wi^T + bi  -> fp16 xg
// smem layout: Ws [0,16384), Es [16384,32768), ids [32768,33280)
// ---------------------------------------------------------------------------
static __device__ void gemm_body(
    unsigned char* smem, int mt, int nt, int dir,
    const int* __restrict__ ids, const float* __restrict__ emb,
    const float* __restrict__ Wi_f, const float* __restrict__ bi_f,
    const float* __restrict__ Wi_b, const float* __restrict__ bi_b,
    int s0_f, int s0_b,
    _Float16* __restrict__ xg_f, _Float16* __restrict__ xg_b)
{
  const float* __restrict__ Wi = dir ? Wi_b : Wi_f;
  const float* __restrict__ bi = dir ? bi_b : bi_f;
  _Float16*   __restrict__ xg  = dir ? xg_b : xg_f;
  const int s0 = dir ? s0_b : s0_f;

  _Float16* Ws = (_Float16*)smem;
  _Float16* Es = (_Float16*)(smem + 16384);
  int* ids_s   = (int*)(smem + 32768);

  const int tid = threadIdx.x;
  if (tid < 128) {
    ids_s[tid] = ids[(tid & 63) * S_LEN + s0 + mt * 2 + (tid >> 6)];
  }

  const int w  = tid >> 6;          // wave 0..3
  const int L  = tid & 63;
  const int lh = L >> 4;            // 0..3
  const int ln = L & 15;            // 0..15
  const int wn = (w >> 1) * 64;     // wave n-base
  const int wm = (w & 1) * 64;      // wave m-base

  const int r  = tid >> 1;          // staging row 0..127
  const int kh = (tid & 1) * 32;    // staging k offset

  f4 acc[4][4];
#pragma unroll
  for (int i = 0; i < 4; ++i)
#pragma unroll
    for (int j = 0; j < 4; ++j) { acc[i][j][0]=0.f; acc[i][j][1]=0.f; acc[i][j][2]=0.f; acc[i][j][3]=0.f; }

  __syncthreads();

  for (int kt = 0; kt < DM; kt += 64) {
    {
      const float* srcW = Wi + (size_t)(nt * 128 + r) * DM + kt + kh;
      const float* srcE = emb + (size_t)ids_s[r] * DM + kt + kh;
      float4 w0 = ((const float4*)srcW)[0], w1 = ((const float4*)srcW)[1];
      float4 w2 = ((const float4*)srcW)[2], w3 = ((const float4*)srcW)[3];
      float4 w4 = ((const float4*)srcW)[4], w5 = ((const float4*)srcW)[5];
      float4 w6 = ((const float4*)srcW)[6], w7 = ((const float4*)srcW)[7];
      float4 e0 = ((const float4*)srcE)[0], e1 = ((const float4*)srcE)[1];
      float4 e2 = ((const float4*)srcE)[2], e3 = ((const float4*)srcE)[3];
      float4 e4 = ((const float4*)srcE)[4], e5 = ((const float4*)srcE)[5];
      float4 e6 = ((const float4*)srcE)[6], e7 = ((const float4*)srcE)[7];
      stfrag(Ws, r, kh + 0,  pack8(w0, w1));
      stfrag(Ws, r, kh + 8,  pack8(w2, w3));
      stfrag(Ws, r, kh + 16, pack8(w4, w5));
      stfrag(Ws, r, kh + 24, pack8(w6, w7));
      stfrag(Es, r, kh + 0,  pack8(e0, e1));
      stfrag(Es, r, kh + 8,  pack8(e2, e3));
      stfrag(Es, r, kh + 16, pack8(e4, e5));
      stfrag(Es, r, kh + 24, pack8(e6, e7));
    }
    __syncthreads();
#pragma unroll
    for (int ks = 0; ks < 2; ++ks) {
      h8 af[4], bf[4];
#pragma unroll
      for (int i = 0; i < 4; ++i) af[i] = ldfrag(Ws, wn + i * 16 + ln, ks * 32 + lh * 8);
#pragma unroll
      for (int j = 0; j < 4; ++j) bf[j] = ldfrag(Es, wm + j * 16 + ln, ks * 32 + lh * 8);
#pragma unroll
      for (int i = 0; i < 4; ++i)
#pragma unroll
        for (int j = 0; j < 4; ++j)
          acc[i][j] = __builtin_amdgcn_mfma_f32_16x16x32_f16(af[i], bf[j], acc[i][j], 0, 0, 0);
    }
    __syncthreads();
  }

#pragma unroll
  for (int i = 0; i < 4; ++i) {
    const int n_g = nt * 128 + wn + i * 16 + lh * 4;
    const int gate = n_g / 768;
    const int jj = n_g - gate * 768;
    const f4 bv = *(const f4*)&bi[n_g];
#pragma unroll
    for (int j = 0; j < 4; ++j) {
      const int m = mt * 128 + wm + j * 16 + ln;
      const int sl = m >> 6, b = m & 63;
      h4 v;
#pragma unroll
      for (int rr = 0; rr < 4; ++rr) v[rr] = (_Float16)(acc[i][j][rr] + bv[rr]);
      *(h4*)&xg[(((size_t)sl * 3 + gate) * 64 + b) * 768 + jj] = v;
    }
  }
}

// standalone gemm (chunk 0): full occupancy
__global__ __launch_bounds__(256) void gemm1_kernel(
    const int* __restrict__ ids, const float* __restrict__ emb,
    const float* __restrict__ Wi_f, const float* __restrict__ bi_f,
    const float* __restrict__ Wi_b, const float* __restrict__ bi_b,
    int s0_f, int s0_b,
    _Float16* __restrict__ xg_f, _Float16* __restrict__ xg_b)
{
  __shared__ __align__(16) unsigned char smem[33280];
  gemm_body(smem, blockIdx.x, blockIdx.y, blockIdx.z,
            ids, emb, Wi_f, bi_f, Wi_b, bi_b, s0_f, s0_b, xg_f, xg_b);
}

// ---------------------------------------------------------------------------
// scan body (device): MFMA GRU scan with value-embedded tags (R11 scheme).
// smem: hs [0, 24576)
// ---------------------------------------------------------------------------
static __device__ void scan_body(
    unsigned char* hs, int blk,
    const float* __restrict__ Wh_f, const float* __restrict__ bh_f,
    const float* __restrict__ Wh_b, const float* __restrict__ bh_b,
    const _Float16* __restrict__ xg_f, const _Float16* __restrict__ xg_b,
    char* __restrict__ hx, float* __restrict__ hfin,
    int step0, int nsteps)
{
  const int dir = blk / 48;
  const int l   = blk - dir * 48;   // 0..47
  const int bg  = l / 12;           // batch group 0..3
  const int jb  = l - bg * 12;      // unit twelfth 0..11

  const float* __restrict__ Wh = dir ? Wh_b : Wh_f;
  const float* __restrict__ bh = dir ? bh_b : bh_f;
  const _Float16* __restrict__ xg = dir ? xg_b : xg_f;
  char*  payB = hx + (size_t)dir * 2 * 64 * 1536;
  float* hfd  = hfin + (size_t)dir * 64 * 768;

  const int tid = threadIdx.x;
  const int w   = tid >> 6;         // wave 0..3
  const int L   = tid & 63;
  const int lh  = L >> 4;           // 0..3
  const int ln  = L & 15;           // 0..15
  const int jt  = jb * 4 + w;       // unit tile 0..47
  const int jrow = jt * 16 + ln;    // A-fragment row (j)
  const int j0l  = jt * 16 + lh * 4;  // 4 owned units
  const int bglob = bg * 16 + ln;   // owned batch column (producer)
  const int bb  = tid >> 4;         // consumer batch row 0..15
  const int qi  = tid & 15;         // consumer pair-group base

  // ---- Wh as A-fragments
  h8 A[3][24];
#pragma unroll
  for (int g = 0; g < 3; ++g)
#pragma unroll
    for (int ks = 0; ks < 24; ++ks) {
      const float* src = Wh + (size_t)(g * 768 + jrow) * 768 + ks * 32 + lh * 8;
      float4 w0 = ((const float4*)src)[0];
      float4 w1 = ((const float4*)src)[1];
      A[g][ks] = pack8(w0, w1);
    }

  f4 bhv[3];
#pragma unroll
  for (int g = 0; g < 3; ++g) bhv[g] = *(const f4*)&bh[g * 768 + j0l];

  // ---- fp32 h master
  f4 hm;
  if (step0 == 0) { hm[0]=0.f; hm[1]=0.f; hm[2]=0.f; hm[3]=0.f; }
  else {
    const float* src = &hfd[(size_t)bglob * 768 + j0l];
    asm volatile("global_load_dwordx4 %0, %1, off sc0 sc1\n\t"
                 "s_waitcnt vmcnt(0)"
                 : "=&v"(hm) : "v"(src) : "memory");
  }

  // producer slot: batch bglob, granule jt*4+lh (4 units), 8B
  char* const pslot = payB + (size_t)bglob * 1536 + (size_t)(jt * 4 + lh) * 8;
  // consumer: batch bb, pair p = qi+16*i at byte qi*16 + 256*i
  const char* const crow = payB + (size_t)(bg * 16 + bb) * 1536 + qi * 16;
  const int swb = (bb ^ (qi & 7)) * 16;   // swizzled LDS column (row&7==qi&7)

  for (int t = 0; t < nsteps; ++t) {
    const int sg = step0 + t;
    const int pin = sg & 1, pout = pin ^ 1;

    // xg loads for this step (overlap the poll's vmcnt)
    const int lsl = dir ? (nsteps - 1 - t) : t;
    const _Float16* xrow = xg + (((size_t)lsl * 3) * 64 + bglob) * 768 + j0l;
    h4 xr4 = *(const h4*)xrow;
    h4 xz4 = *(const h4*)(xrow + (size_t)64 * 768);
    h4 xn4 = *(const h4*)(xrow + (size_t)2 * 64 * 768);

    // ---- poll payload until all 12 embedded tags == sg&15
    const u32 texp = (u32)sg & 15u;
    const u32 e0 = ((texp & 1u) << 14) | ((texp & 2u) << 29);
    const u32 e1 = ((texp & 4u) << 12) | ((texp & 8u) << 27);
    const char* pc = crow + (size_t)pin * 64 * 1536;
    u64 q0,q1,q2,q3,q4,q5,q6,q7,q8,q9,q10,q11;
    for (;;) {
      asm volatile(
        "global_load_dwordx2 %0, %12, off sc0 sc1\n\t"
        "global_load_dwordx2 %1, %12, off offset:8 sc0 sc1\n\t"
        "global_load_dwordx2 %2, %13, off sc0 sc1\n\t"
        "global_load_dwordx2 %3, %13, off offset:8 sc0 sc1\n\t"
        "global_load_dwordx2 %4, %14, off sc0 sc1\n\t"
        "global_load_dwordx2 %5, %14, off offset:8 sc0 sc1\n\t"
        "global_load_dwordx2 %6, %15, off sc0 sc1\n\t"
        "global_load_dwordx2 %7, %15, off offset:8 sc0 sc1\n\t"
        "global_load_dwordx2 %8, %16, off sc0 sc1\n\t"
        "global_load_dwordx2 %9, %16, off offset:8 sc0 sc1\n\t"
        "global_load_dwordx2 %10, %17, off sc0 sc1\n\t"
        "global_load_dwordx2 %11, %17, off offset:8 sc0 sc1\n\t"
        "s_waitcnt vmcnt(0)"
        : "=&v"(q0), "=&v"(q1), "=&v"(q2), "=&v"(q3), "=&v"(q4), "=&v"(q5),
          "=&v"(q6), "=&v"(q7), "=&v"(q8), "=&v"(q9), "=&v"(q10), "=&v"(q11)
        : "v"(pc), "v"(pc + 256), "v"(pc + 512),
          "v"(pc + 768), "v"(pc + 1024), "v"(pc + 1280)
        : "memory");
      u32 bad = 0;
      u64 qs[12] = {q0,q1,q2,q3,q4,q5,q6,q7,q8,q9,q10,q11};
#pragma unroll
      for (int i = 0; i < 12; ++i) {
        u32 lo = (u32)qs[i], hi = (u32)(qs[i] >> 32);
        bad |= ((lo & 0x40004000u) ^ e0) | ((hi & 0x40004000u) ^ e1);
      }
      if (bad == 0) break;
    }
    // clear tag bits and stage to LDS (pair rows qi+16i, swizzled col)
    {
      const u64 CM = 0xBFFFBFFFBFFFBFFFull;
      u64 qa[12] = {q0&CM,q1&CM,q2&CM,q3&CM,q4&CM,q5&CM,q6&CM,q7&CM,q8&CM,q9&CM,q10&CM,q11&CM};
#pragma unroll
      for (int i = 0; i < 6; ++i) {
        u64* d = (u64*)(hs + (qi + 16 * i) * 256 + swb);
        d[0] = qa[2 * i];
        d[1] = qa[2 * i + 1];
      }
    }
    __syncthreads();

    // ---- B-fragments from LDS + MFMA  (pair row p = ks*4+lh)
    f4 Cr, Cz, Cn;
    Cr[0]=0.f;Cr[1]=0.f;Cr[2]=0.f;Cr[3]=0.f;
    Cz = Cr; Cn = Cr;
#pragma unroll
    for (int ks = 0; ks < 24; ++ks) {
      const int p = ks * 4 + lh;
      h8 Bf = *(const h8*)(hs + p * 256 + ((ln ^ (p & 7)) * 16));
      Cr = __builtin_amdgcn_mfma_f32_16x16x32_f16(A[0][ks], Bf, Cr, 0, 0, 0);
      Cz = __builtin_amdgcn_mfma_f32_16x16x32_f16(A[1][ks], Bf, Cz, 0, 0, 0);
      Cn = __builtin_amdgcn_mfma_f32_16x16x32_f16(A[2][ks], Bf, Cn, 0, 0, 0);
    }

    // ---- gates
    f4 hnew;
    h4u st;
#pragma unroll
    for (int r = 0; r < 4; ++r) {
      float rr = 1.f / (1.f + __expf(-((float)xr4[r] + Cr[r] + bhv[0][r])));
      float zz = 1.f / (1.f + __expf(-((float)xz4[r] + Cz[r] + bhv[1][r])));
      float nn = tanhf((float)xn4[r] + rr * (Cn[r] + bhv[2][r]));
      hnew[r] = (1.f - zz) * nn + zz * hm[r];
      st.v[r] = (_Float16)fminf(1.f, fmaxf(-1.f, hnew[r]));
    }
    hm = hnew;

    // ---- producer: embed tag (sg+1)&15 in bit14s, single 8B store
    {
      const u32 tw = (u32)(sg + 1) & 15u;
      u32 lo = (u32)st.u, hi = (u32)(st.u >> 32);
      lo |= ((tw & 1u) << 14) | ((tw & 2u) << 29);
      hi |= ((tw & 4u) << 12) | ((tw & 8u) << 27);
      u64 pv = ((u64)hi << 32) | lo;
      char* dst = pslot + (size_t)pout * 64 * 1536;
      asm volatile("global_store_dwordx2 %0, %1, off sc0 sc1"
                   :: "v"(dst), "v"(pv) : "memory");
    }
    __syncthreads();   // protect hs reuse next iteration
  }

  // chunk-save fp32 h
  {
    float* dst = &hfd[(size_t)bglob * 768 + j0l];
    asm volatile("global_store_dwordx4 %0, %1, off sc0 sc1"
                 :: "v"(dst), "v"(hm) : "memory");
  }
}

// ---------------------------------------------------------------------------
// Fused kernel: blocks 0..95 scan chunk c; blocks 96.. gemm chunk c+1.
// Safety: gemm blocks never wait (always retire); scan blocks dispatched
// first and only wait on each other -> co-residency guaranteed.
// ---------------------------------------------------------------------------
__global__ __launch_bounds__(256, 1) void fused_kernel(
    const float* __restrict__ Wh_f, const float* __restrict__ bh_f,
    const float* __restrict__ Wh_b, const float* __restrict__ bh_b,
    const _Float16* __restrict__ sxg_f, const _Float16* __restrict__ sxg_b,
    char* __restrict__ hx, float* __restrict__ hfin, int step0, int nsteps,
    const int* __restrict__ ids, const float* __restrict__ emb,
    const float* __restrict__ Wi_f, const float* __restrict__ bi_f,
    const float* __restrict__ Wi_b, const float* __restrict__ bi_b,
    int g_s0f, int g_s0b,
    _Float16* __restrict__ gxg_f, _Float16* __restrict__ gxg_b, int mtc)
{
  __shared__ __align__(16) unsigned char smem[33280];
  const int b = blockIdx.x;
  if (b < 96) {
    scan_body(smem, b, Wh_f, bh_f, Wh_b, bh_b, sxg_f, sxg_b,
              hx, hfin, step0, nsteps);
  } else {
    const int e = b - 96;
    const int mt = e % mtc;
    const int r2 = e / mtc;
    const int nt = r2 % 18;
    const int dir = r2 / 18;
    gemm_body(smem, mt, nt, dir, ids, emb, Wi_f, bi_f, Wi_b, bi_b,
              g_s0f, g_s0b, gxg_f, gxg_b);
  }
}

// ---------------------------------------------------------------------------
// MLP head.  hfin layout: [dir][b][j] fp32.
// ---------------------------------------------------------------------------
__global__ __launch_bounds__(256) void mlp1_kernel(
    const float* __restrict__ hfin, const float* __restrict__ W1,
    const float* __restrict__ b1, float* __restrict__ hid)
{
  const int c = blockIdx.x * 4 + (threadIdx.x >> 6);
  const int b = threadIdx.x & 63;
  const float* __restrict__ hf = hfin + (size_t)b * 768;
  const float* __restrict__ hb = hfin + (size_t)(64 + b) * 768;
  const float* __restrict__ w = W1 + (size_t)c * 1536;
  float acc = b1[c];
  for (int k = 0; k < 768; k += 4) {
    float4 hv = *(const float4*)&hf[k];
    float4 wv = *(const float4*)&w[k];
    acc += hv.x * wv.x + hv.y * wv.y + hv.z * wv.z + hv.w * wv.w;
  }
  for (int k = 0; k < 768; k += 4) {
    float4 hv = *(const float4*)&hb[k];
    float4 wv = *(const float4*)&w[768 + k];
    acc += hv.x * wv.x + hv.y * wv.y + hv.z * wv.z + hv.w * wv.w;
  }
  hid[(size_t)c * 64 + b] = fmaxf(acc, 0.f);
}

__global__ void mlp2_kernel(const float* __restrict__ hid,
                            const float* __restrict__ W2,
                            const float* __restrict__ b2,
                            float* __restrict__ out)
{
  const int tid = threadIdx.x;      // 128 threads
  const int b = tid & 63, cls = tid >> 6;
  const float* __restrict__ w = W2 + cls * 768;
  float acc = b2[cls];
  for (int k = 0; k < 768; ++k) acc += hid[(size_t)k * 64 + b] * w[k];
  out[b * 2 + cls] = acc;
}

// ---------------------------------------------------------------------------
extern "C" void kernel_launch(void* const* d_in, const int* in_sizes, int n_in,
                              void* d_out, int out_size, void* d_ws, size_t ws_size,
                              hipStream_t stream)
{
  const int*   ids  = (const int*)d_in[0];
  const float* emb  = (const float*)d_in[1];
  const float* Wi_f = (const float*)d_in[2];
  const float* Wh_f = (const float*)d_in[3];
  const float* bi_f = (const float*)d_in[4];
  const float* bh_f = (const float*)d_in[5];
  const float* Wi_b = (const float*)d_in[6];
  const float* Wh_b = (const float*)d_in[7];
  const float* bi_b = (const float*)d_in[8];
  const float* bh_b = (const float*)d_in[9];
  const float* W1   = (const float*)d_in[10];
  const float* b1   = (const float*)d_in[11];
  const float* W2   = (const float*)d_in[12];
  const float* b2   = (const float*)d_in[13];
  float* out = (float*)d_out;

  // state sizes (bytes)
  const size_t B_HX   = (size_t)2 * 2 * 64 * 1536;      // 393216
  const size_t B_HFIN = (size_t)2 * 64 * 768 * 4;       // 393216
  const size_t B_HID  = (size_t)HID * BATCH * 4;        // 196608
  const size_t state_bytes = B_HX + B_HFIN + B_HID;

  // choose chunk size: largest CH with DOUBLE-buffered xg + state <= ws
  int CH = 512;
  while (CH > 8) {
    size_t need = (size_t)8 * CH * 64 * 2304 + state_bytes;
    if (need <= ws_size) break;
    CH >>= 1;
  }
  const size_t SZ_XG = (size_t)CH * 64 * 2304;      // halves per dir per buf

  char* ws = (char*)d_ws;
  _Float16* xgbuf0 = (_Float16*)ws;                 // buf0: [f][b]
  _Float16* xgbuf1 = xgbuf0 + 2 * SZ_XG;            // buf1: [f][b]
  char*     hx   = (char*)(xgbuf1 + 2 * SZ_XG);
  float*    hfin = (float*)(hx + B_HX);
  float*    hid  = (float*)((char*)hfin + B_HFIN);

  // zero hx + hfin + hid (contiguous) every call
  (void)hipMemsetAsync(hx, 0, state_bytes, stream);

  const int nch = 512 / CH;
  // chunk 0 gemm at full occupancy
  gemm1_kernel<<<dim3(CH / 2, 18, 2), 256, 0, stream>>>(
      ids, emb, Wi_f, bi_f, Wi_b, bi_b, 0, 512 - CH, xgbuf0, xgbuf0 + SZ_XG);

  for (int c = 0; c < nch; ++c) {
    _Float16* sf = (c & 1) ? xgbuf1 : xgbuf0;
    _Float16* gf = (c & 1) ? xgbuf0 : xgbuf1;
    const int ng = (c + 1 < nch) ? (CH / 2) * 36 : 0;
    fused_kernel<<<96 + ng, 256, 0, stream>>>(
        Wh_f, bh_f, Wh_b, bh_b, sf, sf + SZ_XG, hx, hfin, c * CH, CH,
        ids, emb, Wi_f, bi_f, Wi_b, bi_b,
        (c + 1) * CH, 512 - (c + 2) * CH, gf, gf + SZ_XG, CH / 2);
  }
  mlp1_kernel<<<192, 256, 0, stream>>>(hfin, W1, b1, hid);
  mlp2_kernel<<<1, 128, 0, stream>>>(hid, W2, b2, out);
}